// Round 14
// baseline (183.819 us; speedup 1.0000x reference)
//
#include <hip/hip_runtime.h>

#define DI __device__ __forceinline__

typedef __attribute__((ext_vector_type(8))) short bh8;
typedef __attribute__((ext_vector_type(4))) float fx4;
typedef __attribute__((ext_vector_type(16))) float fx16;

DI short f2bf(float f) {
  unsigned u = __builtin_bit_cast(unsigned, f);
  u += 0x7FFFu + ((u >> 16) & 1u);
  return (short)(u >> 16);
}
DI float bf2f(short s) {
  unsigned u = ((unsigned)(unsigned short)s) << 16;
  return __builtin_bit_cast(float, u);
}
DI fx4 mfma16(bh8 a, bh8 b, fx4 c) {
  return __builtin_amdgcn_mfma_f32_16x16x32_bf16(a, b, c, 0, 0, 0);
}
DI fx16 mfma32(bh8 a, bh8 b, fx16 c) {
  return __builtin_amdgcn_mfma_f32_32x32x16_bf16(a, b, c, 0, 0, 0);
}
DI fx4 fzero() { fx4 z = {0.f, 0.f, 0.f, 0.f}; return z; }

DI float fexp2(float x) {
#if __has_builtin(__builtin_amdgcn_exp2f)
  return __builtin_amdgcn_exp2f(x);
#else
  return exp2f(x);
#endif
}

DI bh8 pack8(const float* src) {
  fx4 v0 = *(const fx4*)src;
  fx4 v1 = *(const fx4*)(src + 4);
  bh8 pk;
#pragma unroll
  for (int j = 0; j < 4; j++) { pk[j] = f2bf(v0[j]); pk[j + 4] = f2bf(v1[j]); }
  return pk;
}

// ---------------- holistic LN stats (partials over x / x1) ----------------
__global__ __launch_bounds__(256) void iln_partial(const float* __restrict__ x,
                                                   float* __restrict__ part) {
  const int blk = blockIdx.x, tid = threadIdx.x;
  const fx4* p = (const fx4*)(x + (size_t)blk * 12288);
  float s = 0.f, s2 = 0.f;
#pragma unroll
  for (int i = 0; i < 12; i++) {
    fx4 v = p[i * 256 + tid];
    s  += v[0] + v[1] + v[2] + v[3];
    s2 += v[0] * v[0] + v[1] * v[1] + v[2] * v[2] + v[3] * v[3];
  }
  __shared__ float sm[512];
  sm[tid] = s; sm[256 + tid] = s2;
  __syncthreads();
  for (int st = 128; st > 0; st >>= 1) {
    if (tid < st) { sm[tid] += sm[tid + st]; sm[256 + tid] += sm[256 + tid + st]; }
    __syncthreads();
  }
  if (tid == 0) { part[blk * 2] = sm[0]; part[blk * 2 + 1] = sm[256]; }
}

// ---------------- prep: weight convert (fragment layout) + bf16 bias table ----------------
__global__ __launch_bounds__(256) void prep(const float* __restrict__ qkv_w,
                                            const float* __restrict__ proj_w,
                                            const float* __restrict__ fcgv_w,
                                            const float* __restrict__ fco_w,
                                            const float* __restrict__ rpb,
                                            short* __restrict__ wbuf,
                                            short* __restrict__ btb) {
  if (blockIdx.x < 216) {
    int t = blockIdx.x * 256 + threadIdx.x;
    int blk = t >> 6, lane = t & 63;
    int g = lane >> 4, h = lane & 15;
    const float* src;
    if (blk < 216) {
      int b2 = blk;
      int ni = b2 % 3; b2 /= 3;
      int wn = b2 & 1; b2 >>= 1;
      int kt = b2 % 6; b2 /= 6;
      int nt = b2;
      src = qkv_w + (size_t)(nt * 96 + wn * 48 + ni * 16 + h) * 192 + kt * 32 + g * 8;
    } else if (blk < 288) {
      int b2 = blk - 216;
      int ni = b2 % 3; b2 /= 3;
      int wn = b2 & 1; b2 >>= 1;
      int kt = b2 % 6; b2 /= 6;
      int nt = b2;
      src = proj_w + (size_t)(nt * 96 + wn * 48 + ni * 16 + h) * 192 + kt * 32 + g * 8;
    } else if (blk < 672) {
      int b2 = blk - 288;
      int gv = b2 & 1; b2 >>= 1;
      int ni = b2 & 1; b2 >>= 1;
      int wn = b2 & 1; b2 >>= 1;
      int kt = b2 % 6; b2 /= 6;
      int nt = b2;
      int r = wn * 32 + ni * 16 + h;
      int row = gv ? (512 + nt * 64 + r) : (nt * 64 + r);
      src = fcgv_w + (size_t)row * 192 + kt * 32 + g * 8;
    } else {
      int b2 = blk - 672;
      int ni = b2 % 3; b2 /= 3;
      int wn = b2 & 1; b2 >>= 1;
      int kt = b2 & 15; b2 >>= 4;
      int nt = b2;
      src = fco_w + (size_t)(nt * 96 + wn * 48 + ni * 16 + h) * 512 + kt * 32 + g * 8;
    }
    *(bh8*)(wbuf + (size_t)blk * 512 + lane * 8) = pack8(src);
  } else {
    int t = (blockIdx.x - 216) * 256 + threadIdx.x;  // 55296
    int lane = t & 63;
    int u = t >> 6;
    int qi = u & 1;
    int c = lane & 31, hi = lane >> 5;
    int w = (u >> 2) / 9 % 4;
    int head = (u >> 2) / 36;
    int q = w * 64 + qi * 32 + c;
    int qterm = (q >> 4) * 39 + (q & 15);
    short o16[16];
#pragma unroll
    for (int r = 0; r < 16; r++) {
      int kk = ((u >> 2) % 9) * 64 + ((u >> 1) & 1) * 32 + (r & 3) + 8 * (r >> 2) + 4 * hi;
      int ky = (kk * 2731) >> 16;
      int kx = kk - ky * 24;
      int idx = ky * 39 + kx + 600 - qterm;
      o16[r] = f2bf(rpb[idx * 6 + head] * 1.4426950408889634f);
    }
    *(bh8*)(btb + (size_t)u * 1024 + lane * 16)     = *(bh8*)&o16[0];
    *(bh8*)(btb + (size_t)u * 1024 + lane * 16 + 8) = *(bh8*)&o16[8];
  }
}

// ---------------- activation convert -> A-fragment layout, with fused iln-final ----------------
__global__ __launch_bounds__(256) void cvt_aff(const float* __restrict__ src,
                                               const float* __restrict__ part,
                                               const float* __restrict__ w,
                                               const float* __restrict__ bias,
                                               short* __restrict__ dst,
                                               float* __restrict__ st) {
  __shared__ float rs[512];
  const int tid = threadIdx.x;
  const int bb = (blockIdx.x >= 1536) ? 1 : 0;
  rs[tid]       = part[(bb * 256 + tid) * 2];
  rs[256 + tid] = part[(bb * 256 + tid) * 2 + 1];
  __syncthreads();
  for (int s = 128; s > 0; s >>= 1) {
    if (tid < s) { rs[tid] += rs[tid + s]; rs[256 + tid] += rs[256 + tid + s]; }
    __syncthreads();
  }
  const float invn = 1.f / 3145728.f;
  float mean = rs[0] * invn;
  float var  = rs[256] * invn - mean * mean;
  float scale = fminf(sqrtf(var + 1e-6f), 2.f);
  if (tid == 0 && (blockIdx.x == 0 || blockIdx.x == 1536)) {
    st[bb * 2] = mean;
    st[bb * 2 + 1] = scale;
  }
  const float isc = 1.f / scale;
  int t = blockIdx.x * 256 + tid;
  int row = t / 24;
  int c0 = (t - row * 24) * 8;
  int mt = row >> 7, wm = (row >> 6) & 1, mi = (row >> 4) & 3, h = row & 15;
  int kt = c0 >> 5, g = (c0 >> 3) & 3;
  int blk = ((mt * 2 + wm) * 4 + mi) * 6 + kt;
  int lane = g * 16 + h;
  const float* sp = src + (size_t)row * 192 + c0;
  fx4 v0 = *(const fx4*)sp;
  fx4 v1 = *(const fx4*)(sp + 4);
  bh8 pk;
#pragma unroll
  for (int j = 0; j < 4; j++) {
    float a = w[c0 + j] * isc;
    pk[j] = f2bf(v0[j] * a + (bias[c0 + j] - mean * a));
  }
#pragma unroll
  for (int j = 0; j < 4; j++) {
    float a = w[c0 + 4 + j] * isc;
    pk[j + 4] = f2bf(v1[j] * a + (bias[c0 + 4 + j] - mean * a));
  }
  *(bh8*)(dst + (size_t)blk * 512 + lane * 8) = pk;
}

// ---------------- QKV GEMM: barrier-free; grid (6 n-tiles, 256 m-tiles) for L2 reuse ----------------
__global__ __launch_bounds__(256) void gemm_qkv(const short* __restrict__ xn,
                                                const short* __restrict__ wq,
                                                const float* __restrict__ wb,
                                                short* __restrict__ qb,
                                                short* __restrict__ kb,
                                                short* __restrict__ vb) {
  const int by = blockIdx.x, mt = blockIdx.y;
  const int m0 = mt * 128;
  const int tid = threadIdx.x, wid = tid >> 6, lane = tid & 63;
  const int g = lane >> 4, h = lane & 15;
  const int wm = wid >> 1, wn = wid & 1;
  fx4 acc[4][3];
#pragma unroll
  for (int i = 0; i < 4; i++)
#pragma unroll
    for (int j = 0; j < 3; j++) acc[i][j] = fzero();

#pragma unroll
  for (int kt = 0; kt < 6; kt++) {
    bh8 af[4], bf[3];
#pragma unroll
    for (int mi = 0; mi < 4; mi++)
      af[mi] = *(const bh8*)(xn + (size_t)((((mt * 2 + wm) * 4 + mi) * 6 + kt)) * 512 + lane * 8);
#pragma unroll
    for (int ni = 0; ni < 3; ni++)
      bf[ni] = *(const bh8*)(wq + (size_t)(((by * 6 + kt) * 2 + wn) * 3 + ni) * 512 + lane * 8);
#pragma unroll
    for (int ni = 0; ni < 3; ni++)
#pragma unroll
      for (int mi = 0; mi < 4; mi++) acc[mi][ni] = mfma16(af[mi], bf[ni], acc[mi][ni]);
  }
  const int seg = by >> 1;
  short* dst = (seg == 0) ? qb : (seg == 1 ? kb : vb);
  const float sc = (seg == 1) ? 0.25503486f : 1.0f;  // SCALE * log2(e) folded into K
  const int colbase = (by & 1) * 96;
#pragma unroll
  for (int mi = 0; mi < 4; mi++)
#pragma unroll
    for (int ni = 0; ni < 3; ni++)
#pragma unroll
      for (int r = 0; r < 4; r++) {
        int row = m0 + wm * 64 + mi * 16 + g * 4 + r;
        int col = colbase + wn * 48 + ni * 16 + h;
        dst[(size_t)row * 192 + col] = f2bf((acc[mi][ni][r] + wb[seg * 192 + col]) * sc);
      }
}

// ---------------- attention: grid (6 heads, 128 windows) -> same-window heads adjacent ----------------
__global__ __launch_bounds__(256, 3) void attn_kernel(const short* __restrict__ qb,
                                                      const short* __restrict__ kb,
                                                      const short* __restrict__ vb,
                                                      const short* __restrict__ btb,
                                                      short* __restrict__ ao) {
  __shared__ short K_lds[64 * 40];
  __shared__ short Vt_lds[32 * 72];
  __shared__ float l_lds[256];
  const int tid = threadIdx.x;
  const int win = blockIdx.y, head = blockIdx.x;
  const int b = win >> 6, wy = (win >> 3) & 7, wx = win & 7;
  const int w = tid >> 6, lane = tid & 63, c = lane & 31, hi = lane >> 5;

  bh8 qf[2][2];
#pragma unroll
  for (int qi = 0; qi < 2; qi++) {
    int ql = w * 64 + qi * 32 + c;
    size_t gl = (size_t)(b * 16384 + (wy * 16 + (ql >> 4)) * 128 + wx * 16 + (ql & 15));
#pragma unroll
    for (int ds = 0; ds < 2; ds++)
      qf[qi][ds] = *(const bh8*)(qb + gl * 192 + head * 32 + ds * 16 + hi * 8);
  }
  float l_run[2] = {0.f, 0.f};
  fx16 out[2];
#pragma unroll
  for (int r = 0; r < 16; r++) { out[0][r] = 0.f; out[1][r] = 0.f; }

  const int hw9 = (head * 4 + w) * 9;

  const int kl_a = tid >> 2, part_a = tid & 3;
  const int kl_b = tid & 63, hg_b = tid >> 6;

  for (int kc = 0; kc < 9; kc++) {
    __syncthreads();
    {
      int key = kc * 64 + kl_a;
      int ky = key / 24, kx = key - ky * 24;
      int py = wy * 16 - 4 + ky, px = wx * 16 - 4 + kx;
      bh8 kv = {};
      if ((unsigned)py < 128u && (unsigned)px < 128u)
        kv = *(const bh8*)(kb + ((size_t)(b * 16384 + py * 128 + px)) * 192 + head * 32 + part_a * 8);
      *(bh8*)&K_lds[kl_a * 40 + part_a * 8] = kv;

      int key2 = kc * 64 + kl_b;
      int ky2 = key2 / 24, kx2 = key2 - ky2 * 24;
      int py2 = wy * 16 - 4 + ky2, px2 = wx * 16 - 4 + kx2;
      bh8 vv = {};
      if ((unsigned)py2 < 128u && (unsigned)px2 < 128u)
        vv = *(const bh8*)(vb + ((size_t)(b * 16384 + py2 * 128 + px2)) * 192 + head * 32 + hg_b * 8);
#pragma unroll
      for (int j = 0; j < 8; j++) Vt_lds[(hg_b * 8 + j) * 72 + kl_b] = vv[j];
    }
    __syncthreads();

    const short* base_kc = btb + (size_t)(hw9 + kc) * 4096 + lane * 16;
#pragma unroll
    for (int ki = 0; ki < 2; ki++) {
      fx16 st[2];
#pragma unroll
      for (int qi = 0; qi < 2; qi++) {
        const short* bp = base_kc + (ki * 2 + qi) * 1024;
        int4 b0 = *(const int4*)bp;
        int4 b1 = *(const int4*)(bp + 8);
#pragma unroll
        for (int d = 0; d < 4; d++) {
          unsigned u0 = ((const unsigned*)&b0)[d];
          unsigned u1 = ((const unsigned*)&b1)[d];
          st[qi][2 * d]     = __builtin_bit_cast(float, u0 << 16);
          st[qi][2 * d + 1] = __builtin_bit_cast(float, u0 & 0xffff0000u);
          st[qi][8 + 2 * d]     = __builtin_bit_cast(float, u1 << 16);
          st[qi][8 + 2 * d + 1] = __builtin_bit_cast(float, u1 & 0xffff0000u);
        }
      }
      __builtin_amdgcn_s_setprio(1);
#pragma unroll
      for (int ds = 0; ds < 2; ds++) {
        bh8 kf = *(bh8*)&K_lds[(ki * 32 + c) * 40 + ds * 16 + hi * 8];
        st[0] = mfma32(kf, qf[0][ds], st[0]);
        st[1] = mfma32(kf, qf[1][ds], st[1]);
      }
      __builtin_amdgcn_s_setprio(0);
#pragma unroll
      for (int qi = 0; qi < 2; qi++) {
        float s = 0.f;
#pragma unroll
        for (int r = 0; r < 16; r++) {
          float p = fexp2(st[qi][r]);
          st[qi][r] = p;
          s += p;
        }
        l_run[qi] += s;
      }
      int dwq[2][2][4];
#pragma unroll
      for (int qi = 0; qi < 2; qi++)
#pragma unroll
        for (int k1 = 0; k1 < 2; k1++)
#pragma unroll
          for (int p01 = 0; p01 < 2; p01++) {
            int rA = 2 * p01 + 8 * k1;
            int A, Bv;
            asm("v_cvt_pk_bf16_f32 %0, %1, %2" : "=v"(A)  : "v"(st[qi][rA]),     "v"(st[qi][rA + 1]));
            asm("v_cvt_pk_bf16_f32 %0, %1, %2" : "=v"(Bv) : "v"(st[qi][rA + 4]), "v"(st[qi][rA + 5]));
#if __has_builtin(__builtin_amdgcn_permlane32_swap)
            auto pr = __builtin_amdgcn_permlane32_swap((unsigned)A, (unsigned)Bv, false, false);
            dwq[qi][k1][p01]     = (int)pr[0];
            dwq[qi][k1][p01 + 2] = (int)pr[1];
#else
            int Ax = __shfl_xor(A, 32);
            int Bx = __shfl_xor(Bv, 32);
            dwq[qi][k1][p01]     = hi ? Bx : A;
            dwq[qi][k1][p01 + 2] = hi ? Bv : Ax;
#endif
          }
      __builtin_amdgcn_s_setprio(1);
#pragma unroll
      for (int k1 = 0; k1 < 2; k1++) {
        bh8 bv2 = *(bh8*)&Vt_lds[c * 72 + (ki * 2 + k1) * 16 + hi * 8];
#pragma unroll
        for (int qi = 0; qi < 2; qi++) {
          int4 t4 = {dwq[qi][k1][0], dwq[qi][k1][1], dwq[qi][k1][2], dwq[qi][k1][3]};
          out[qi] = mfma32(__builtin_bit_cast(bh8, t4), bv2, out[qi]);
        }
      }
      __builtin_amdgcn_s_setprio(0);
    }
  }
#pragma unroll
  for (int qi = 0; qi < 2; qi++) {
    float lp = l_run[qi] + __shfl_xor(l_run[qi], 32);
    l_lds[w * 64 + qi * 32 + c] = 1.f / lp;
  }
  __syncthreads();
#pragma unroll
  for (int qi = 0; qi < 2; qi++)
#pragma unroll
    for (int r = 0; r < 16; r++) {
      int row = (r & 3) + 8 * (r >> 2) + 4 * hi;
      float val = out[qi][r] * l_lds[w * 64 + qi * 32 + row];
      int ql = w * 64 + qi * 32 + row;
      ao[((size_t)(win * 256 + ql)) * 192 + head * 32 + c] = f2bf(val);
    }
}

// ---------------- proj GEMM: grid (2 n-tiles, 256 m-tiles); barrier-free loop ----------------
__global__ __launch_bounds__(256) void gemm_proj(const short* __restrict__ ao,
                                                 const short* __restrict__ wp,
                                                 const float* __restrict__ wb,
                                                 const float* __restrict__ x,
                                                 const float* __restrict__ ls1,
                                                 const float* __restrict__ st,
                                                 float* __restrict__ x1,
                                                 float* __restrict__ part2) {
  __shared__ float red[512];
  const int by = blockIdx.x, mt = blockIdx.y;
  const int m0 = mt * 128;
  const int tid = threadIdx.x, wid = tid >> 6, lane = tid & 63;
  const int g = lane >> 4, h = lane & 15;
  const int wm = wid >> 1, wn = wid & 1;
  fx4 acc[4][3];
#pragma unroll
  for (int i = 0; i < 4; i++)
#pragma unroll
    for (int j = 0; j < 3; j++) acc[i][j] = fzero();

#pragma unroll
  for (int kt = 0; kt < 6; kt++) {
    bh8 af[4], bf[3];
#pragma unroll
    for (int mi = 0; mi < 4; mi++)
      af[mi] = *(const bh8*)(ao + (size_t)(m0 + wm * 64 + mi * 16 + h) * 192 + kt * 32 + g * 8);
#pragma unroll
    for (int ni = 0; ni < 3; ni++)
      bf[ni] = *(const bh8*)(wp + (size_t)(((by * 6 + kt) * 2 + wn) * 3 + ni) * 512 + lane * 8);
#pragma unroll
    for (int ni = 0; ni < 3; ni++)
#pragma unroll
      for (int mi = 0; mi < 4; mi++) acc[mi][ni] = mfma16(af[mi], bf[ni], acc[mi][ni]);
  }
  const int n0 = by * 96;
  float ps = 0.f, ps2 = 0.f;
#pragma unroll
  for (int mi = 0; mi < 4; mi++)
#pragma unroll
    for (int ni = 0; ni < 3; ni++)
#pragma unroll
      for (int r = 0; r < 4; r++) {
        int grow = m0 + wm * 64 + mi * 16 + g * 4 + r;
        int win = grow >> 8, q = grow & 255;
        int bb = win >> 6, wy = (win >> 3) & 7, wxx = win & 7;
        int l = (wy * 16 + (q >> 4)) * 128 + wxx * 16 + (q & 15);
        int col = n0 + wn * 48 + ni * 16 + h;
        size_t di = ((size_t)(bb * 16384 + l)) * 192 + col;
        float s1 = st[bb * 2 + 1];
        float val = x[di] + s1 * ls1[col] * (acc[mi][ni][r] + wb[col]);
        x1[di] = val;
        ps += val;
        ps2 += val * val;
      }
  red[tid] = ps; red[256 + tid] = ps2;
  __syncthreads();
  for (int s = 128; s > 0; s >>= 1) {
    if (tid < s) { red[tid] += red[tid + s]; red[256 + tid] += red[256 + tid + s]; }
    __syncthreads();
  }
  if (tid == 0) {
    int pi = mt * 2 + by;
    part2[pi * 2] = red[0];
    part2[pi * 2 + 1] = red[256];
  }
}

// ---------------- fcgv GEMM: grid (8 n-tiles, 256 m-tiles); barrier-free + SiLU -> planar hp ----------------
__global__ __launch_bounds__(256) void gemm_fcgv(const short* __restrict__ x1n,
                                                 const short* __restrict__ wg,
                                                 const float* __restrict__ wb,
                                                 short* __restrict__ hp) {
  __shared__ short T[64 * 136];
  const int by = blockIdx.x, mt = blockIdx.y, n0 = by * 64;
  const int m0 = mt * 128;
  const int b = m0 >> 14, l0 = m0 & 16383;
  const int tid = threadIdx.x, wid = tid >> 6, lane = tid & 63;
  const int g = lane >> 4, h = lane & 15;
  const int wm = wid >> 1, wn = wid & 1;
  fx4 accg[4][2], accv[4][2];
#pragma unroll
  for (int i = 0; i < 4; i++)
#pragma unroll
    for (int j = 0; j < 2; j++) { accg[i][j] = fzero(); accv[i][j] = fzero(); }

#pragma unroll
  for (int kt = 0; kt < 6; kt++) {
    bh8 af[4], bg[2], bv[2];
#pragma unroll
    for (int mi = 0; mi < 4; mi++)
      af[mi] = *(const bh8*)(x1n + (size_t)((((mt * 2 + wm) * 4 + mi) * 6 + kt)) * 512 + lane * 8);
#pragma unroll
    for (int ni = 0; ni < 2; ni++) {
      size_t base = (size_t)((((by * 6 + kt) * 2 + wn) * 2 + ni) * 2) * 512;
      bg[ni] = *(const bh8*)(wg + base + lane * 8);
      bv[ni] = *(const bh8*)(wg + base + 512 + lane * 8);
    }
#pragma unroll
    for (int ni = 0; ni < 2; ni++)
#pragma unroll
      for (int mi = 0; mi < 4; mi++) {
        accg[mi][ni] = mfma16(af[mi], bg[ni], accg[mi][ni]);
        accv[mi][ni] = mfma16(af[mi], bv[ni], accv[mi][ni]);
      }
  }
  short hs[4][2][4];
#pragma unroll
  for (int mi = 0; mi < 4; mi++)
#pragma unroll
    for (int ni = 0; ni < 2; ni++)
#pragma unroll
      for (int r = 0; r < 4; r++) {
        int colg = n0 + wn * 32 + ni * 16 + h;
        float gv = accg[mi][ni][r] + wb[colg];
        float vv = accv[mi][ni][r] + wb[512 + colg];
        hs[mi][ni][r] = f2bf(gv / (1.f + __expf(-gv)) * vv);
      }
#pragma unroll
  for (int mi = 0; mi < 4; mi++)
#pragma unroll
    for (int ni = 0; ni < 2; ni++)
#pragma unroll
      for (int r = 0; r < 4; r++) {
        int cc = wn * 32 + ni * 16 + h;
        int rl = wm * 64 + mi * 16 + g * 4 + r;
        T[cc * 136 + rl] = hs[mi][ni][r];
      }
  __syncthreads();
#pragma unroll
  for (int i = 0; i < 4; i++) {
    int ch = tid + i * 256;
    int cc = ch >> 4, lg = ch & 15;
    bh8 v = *(bh8*)&T[cc * 136 + lg * 8];
    *(bh8*)(hp + (((size_t)(b * 512 + n0 + cc)) << 14) + l0 + lg * 8) = v;
  }
}

// ---------------- fused depthwise convs: 64-row stripes, out-of-place ----------------
__global__ __launch_bounds__(256) void dw_fused(const short* __restrict__ in,
                                                const float* __restrict__ w1,
                                                const float* __restrict__ b1,
                                                const float* __restrict__ w2,
                                                const float* __restrict__ b2,
                                                const float* __restrict__ dsc,
                                                short* __restrict__ outp) {
  __shared__ short P[70 * 136];
  __shared__ short D[68 * 136];
  const int p = blockIdx.x >> 1, s = blockIdx.x & 1, c = p & 511;
  const int tid = threadIdx.x;
  const int r0 = s * 64;
  const int plo = s ? 61 : 0;
  const int pbase = r0 - 3;
  const int dlo = s ? 62 : 0;
  const int dbase = r0 - 2;
  const short* ip = in + ((size_t)p << 14);

  for (int i = tid; i < 67 * 16; i += 256) {
    int rr = plo + (i >> 4), sl = i & 15;
    bh8 v = *(const bh8*)(ip + rr * 128 + sl * 8);
    *(bh8*)&P[(rr - pbase) * 136 + sl * 8] = v;
  }
  float k1[9], k2[9];
#pragma unroll
  for (int j = 0; j < 9; j++) { k1[j] = w1[c * 9 + j]; k2[j] = w2[c * 9 + j]; }
  const float bias1 = b1[c], bias2 = b2[c], ds = dsc[0];
  __syncthreads();

  for (int i = tid; i < 66 * 16; i += 256) {
    int gy = dlo + (i >> 4);
    int x0 = (i & 15) * 8;
    float acc[8];
#pragma unroll
    for (int q = 0; q < 8; q++) acc[q] = bias1;
#pragma unroll
    for (int ky = 0; ky < 3; ky++) {
      int yy = gy + ky - 1;
      if ((unsigned)yy < 128u) {
        const short* row = &P[(yy - pbase) * 136];
        float f[10];
        bh8 v = *(const bh8*)&row[x0];
#pragma unroll
        for (int j = 0; j < 8; j++) f[j + 1] = bf2f(v[j]);
        f[0] = (x0 == 0) ? 0.f : bf2f(row[x0 - 1]);
        f[9] = (x0 == 120) ? 0.f : bf2f(row[x0 + 8]);
        float w0 = k1[ky * 3], wA = k1[ky * 3 + 1], wB = k1[ky * 3 + 2];
#pragma unroll
        for (int q = 0; q < 8; q++) acc[q] += f[q] * w0 + f[q + 1] * wA + f[q + 2] * wB;
      }
    }
    bh8 pk;
#pragma unroll
    for (int q = 0; q < 8; q++) pk[q] = f2bf(acc[q]);
    *(bh8*)&D[(gy - dbase) * 136 + x0] = pk;
  }
  __syncthreads();

  for (int i = tid; i < 64 * 16; i += 256) {
    int gy = r0 + (i >> 4);
    int x0 = (i & 15) * 8;
    float acc[8], center[8];
#pragma unroll
    for (int q = 0; q < 8; q++) acc[q] = bias2;
#pragma unroll
    for (int ky = 0; ky < 3; ky++) {
      int yy = gy + (ky - 1) * 2;
      if ((unsigned)yy < 128u) {
        const short* row = &D[(yy - dbase) * 136];
        float f[12];
        bh8 v = *(const bh8*)&row[x0];
#pragma unroll
        for (int j = 0; j < 8; j++) f[j + 2] = bf2f(v[j]);
        if (x0 == 0) { f[0] = 0.f; f[1] = 0.f; }
        else {
          unsigned lp = *(const unsigned*)&row[x0 - 2];
          f[0] = __builtin_bit_cast(float, lp << 16);
          f[1] = __builtin_bit_cast(float, lp & 0xffff0000u);
        }
        if (x0 == 120) { f[10] = 0.f; f[11] = 0.f; }
        else {
          unsigned rp = *(const unsigned*)&row[x0 + 8];
          f[10] = __builtin_bit_cast(float, rp << 16);
          f[11] = __builtin_bit_cast(float, rp & 0xffff0000u);
        }
        float w0 = k2[ky * 3], wA = k2[ky * 3 + 1], wB = k2[ky * 3 + 2];
#pragma unroll
        for (int q = 0; q < 8; q++) acc[q] += f[q] * w0 + f[q + 2] * wA + f[q + 4] * wB;
        if (ky == 1) {
#pragma unroll
          for (int q = 0; q < 8; q++) center[q] = f[q + 2];
        }
      }
    }
    bh8 pk;
#pragma unroll
    for (int q = 0; q < 8; q++) pk[q] = f2bf(center[q] + ds * acc[q]);
    *(bh8*)(outp + ((size_t)p << 14) + gy * 128 + x0) = pk;
  }
}

// ---------------- fco GEMM: grid (2 n-tiles, 256 m-tiles); dbuf A staging, B fragments ----------------
__global__ __launch_bounds__(256) void gemm_fco(const short* __restrict__ h2,
                                                const short* __restrict__ wo,
                                                const float* __restrict__ wb,
                                                const float* __restrict__ x1,
                                                const float* __restrict__ ls2,
                                                const float* __restrict__ st,
                                                float* __restrict__ out) {
  __shared__ short As[2][128 * 40];
  const int by = blockIdx.x, mt = blockIdx.y, n0 = by * 96;
  const int m0 = mt * 128;
  const int b = m0 >> 14, l0 = m0 & 16383;
  const int tid = threadIdx.x, wid = tid >> 6, lane = tid & 63;
  const int g = lane >> 4, h = lane & 15;
  const int wm = wid >> 1, wn = wid & 1;
  const int cp = tid & 15, lg = tid >> 4;
  fx4 acc[4][3];
#pragma unroll
  for (int i = 0; i < 4; i++)
#pragma unroll
    for (int j = 0; j < 3; j++) acc[i][j] = fzero();

  auto loadA = [&](int kt, bh8& v0, bh8& v1) {
    const short* basep = h2 + (((size_t)(b * 512 + kt * 32 + 2 * cp)) << 14) + l0 + lg * 8;
    v0 = *(const bh8*)basep;
    v1 = *(const bh8*)(basep + 16384);
  };
  auto writeA = [&](int buf, bh8 v0, bh8 v1) {
#pragma unroll
    for (int j = 0; j < 8; j++) {
      unsigned pkv = (unsigned)(unsigned short)v0[j] | (((unsigned)(unsigned short)v1[j]) << 16);
      *(unsigned*)&As[buf][(lg * 8 + j) * 40 + 2 * cp] = pkv;
    }
  };
  {
    bh8 c0, c1;
    loadA(0, c0, c1);
    writeA(0, c0, c1);
  }
  int cur = 0;
  for (int kt = 0; kt < 16; kt++) {
    __syncthreads();
    bh8 n0v, n1v;
    if (kt < 15) loadA(kt + 1, n0v, n1v);
    bh8 af[4], bf[3];
#pragma unroll
    for (int mi = 0; mi < 4; mi++)
      af[mi] = *(bh8*)&As[cur][(wm * 64 + mi * 16 + h) * 40 + g * 8];
#pragma unroll
    for (int ni = 0; ni < 3; ni++)
      bf[ni] = *(const bh8*)(wo + (size_t)(((by * 16 + kt) * 2 + wn) * 3 + ni) * 512 + lane * 8);
#pragma unroll
    for (int ni = 0; ni < 3; ni++)
#pragma unroll
      for (int mi = 0; mi < 4; mi++) acc[mi][ni] = mfma16(af[mi], bf[ni], acc[mi][ni]);
    if (kt < 15) writeA(cur ^ 1, n0v, n1v);
    cur ^= 1;
  }
  float s2 = st[b * 2 + 1];
#pragma unroll
  for (int mi = 0; mi < 4; mi++)
#pragma unroll
    for (int ni = 0; ni < 3; ni++)
#pragma unroll
      for (int r = 0; r < 4; r++) {
        int row = m0 + wm * 64 + mi * 16 + g * 4 + r;
        int col = n0 + wn * 48 + ni * 16 + h;
        size_t di = (size_t)row * 192 + col;
        out[di] = x1[di] + s2 * ls2[col] * (acc[mi][ni][r] + wb[col]);
      }
}

extern "C" void kernel_launch(void* const* d_in, const int* in_sizes, int n_in,
                              void* d_out, int out_size, void* d_ws, size_t ws_size,
                              hipStream_t stream) {
  const float* x      = (const float*)d_in[0];
  const float* qkv_w  = (const float*)d_in[1];
  const float* qkv_b  = (const float*)d_in[2];
  const float* proj_w = (const float*)d_in[3];
  const float* proj_b = (const float*)d_in[4];
  const float* rpb    = (const float*)d_in[5];
  const float* n1_w   = (const float*)d_in[6];
  const float* n1_b   = (const float*)d_in[7];
  const float* ls1    = (const float*)d_in[8];
  const float* n2_w   = (const float*)d_in[9];
  const float* n2_b   = (const float*)d_in[10];
  const float* ls2    = (const float*)d_in[11];
  const float* fcgv_w = (const float*)d_in[12];
  const float* fcgv_b = (const float*)d_in[13];
  const float* dw_w   = (const float*)d_in[14];
  const float* dw_b   = (const float*)d_in[15];
  const float* dwd_w  = (const float*)d_in[16];
  const float* dwd_b  = (const float*)d_in[17];
  const float* dil    = (const float*)d_in[18];
  const float* fco_w  = (const float*)d_in[19];
  const float* fco_b  = (const float*)d_in[20];
  float* out = (float*)d_out;
  char* ws = (char*)d_ws;

  // workspace layout (bytes); peak ~104.5 MB
  short* wbuf = (short*)(ws + 0);
  short* wq = wbuf;
  short* wp = wbuf + 110592;
  short* wg = wbuf + 147456;
  short* wo = wbuf + 344064;
  float* part  = (float*)(ws + 884736);
  float* st1   = (float*)(ws + 891904);
  float* st2   = (float*)(ws + 891968);
  float* part2 = (float*)(ws + 892032);
  short* xn  = (short*)(ws + 1048576);
  short* btb = (short*)(ws + 13631488);
  short* qb  = (short*)(ws + 17301504);
  short* kb  = (short*)(ws + 29884416);
  short* vb  = (short*)(ws + 42467328);
  short* ao  = (short*)(ws + 55050240);
  float* x1  = (float*)(ws + 1048576);
  short* x1n = (short*)(ws + 26214400);
  short* hp  = (short*)(ws + 42467328);
  short* h2  = (short*)(ws + 76021760);

  iln_partial<<<512, 256, 0, stream>>>(x, part);
  prep<<<432, 256, 0, stream>>>(qkv_w, proj_w, fcgv_w, fco_w, rpb, wbuf, btb);
  cvt_aff<<<3072, 256, 0, stream>>>(x, part, n1_w, n1_b, xn, st1);
  gemm_qkv<<<dim3(6, 256), 256, 0, stream>>>(xn, wq, qkv_b, qb, kb, vb);
  attn_kernel<<<dim3(6, 128), 256, 0, stream>>>(qb, kb, vb, btb, ao);
  gemm_proj<<<dim3(2, 256), 256, 0, stream>>>(ao, wp, proj_b, x, ls1, st1, x1, part2);
  cvt_aff<<<3072, 256, 0, stream>>>(x1, part2, n2_w, n2_b, x1n, st2);
  gemm_fcgv<<<dim3(8, 256), 256, 0, stream>>>(x1n, wg, fcgv_b, hp);
  dw_fused<<<2048, 256, 0, stream>>>(hp, dw_w, dw_b, dwd_w, dwd_b, dil, h2);
  gemm_fco<<<dim3(2, 256), 256, 0, stream>>>(h2, wo, fco_b, x1, ls2, st2, out);
}

// Round 15
// 173.356 us; speedup vs baseline: 1.0604x; 1.0604x over previous
//
#include <hip/hip_runtime.h>

#define DI __device__ __forceinline__

typedef __attribute__((ext_vector_type(8))) short bh8;
typedef __attribute__((ext_vector_type(4))) float fx4;
typedef __attribute__((ext_vector_type(16))) float fx16;

DI short f2bf(float f) {
  unsigned u = __builtin_bit_cast(unsigned, f);
  u += 0x7FFFu + ((u >> 16) & 1u);
  return (short)(u >> 16);
}
DI float bf2f(short s) {
  unsigned u = ((unsigned)(unsigned short)s) << 16;
  return __builtin_bit_cast(float, u);
}
DI fx4 mfma16(bh8 a, bh8 b, fx4 c) {
  return __builtin_amdgcn_mfma_f32_16x16x32_bf16(a, b, c, 0, 0, 0);
}
DI fx16 mfma32(bh8 a, bh8 b, fx16 c) {
  return __builtin_amdgcn_mfma_f32_32x32x16_bf16(a, b, c, 0, 0, 0);
}
DI fx4 fzero() { fx4 z = {0.f, 0.f, 0.f, 0.f}; return z; }

DI float fexp2(float x) {
#if __has_builtin(__builtin_amdgcn_exp2f)
  return __builtin_amdgcn_exp2f(x);
#else
  return exp2f(x);
#endif
}

DI bh8 pack8(const float* src) {
  fx4 v0 = *(const fx4*)src;
  fx4 v1 = *(const fx4*)(src + 4);
  bh8 pk;
#pragma unroll
  for (int j = 0; j < 4; j++) { pk[j] = f2bf(v0[j]); pk[j + 4] = f2bf(v1[j]); }
  return pk;
}

// ---------------- holistic LN stats (partials over x / x1) ----------------
__global__ __launch_bounds__(256) void iln_partial(const float* __restrict__ x,
                                                   float* __restrict__ part) {
  const int blk = blockIdx.x, tid = threadIdx.x;
  const fx4* p = (const fx4*)(x + (size_t)blk * 12288);
  float s = 0.f, s2 = 0.f;
#pragma unroll
  for (int i = 0; i < 12; i++) {
    fx4 v = p[i * 256 + tid];
    s  += v[0] + v[1] + v[2] + v[3];
    s2 += v[0] * v[0] + v[1] * v[1] + v[2] * v[2] + v[3] * v[3];
  }
  __shared__ float sm[512];
  sm[tid] = s; sm[256 + tid] = s2;
  __syncthreads();
  for (int st = 128; st > 0; st >>= 1) {
    if (tid < st) { sm[tid] += sm[tid + st]; sm[256 + tid] += sm[256 + tid + st]; }
    __syncthreads();
  }
  if (tid == 0) { part[blk * 2] = sm[0]; part[blk * 2 + 1] = sm[256]; }
}

// ---------------- prep: weight convert (fragment layout) + bf16 bias table ----------------
__global__ __launch_bounds__(256) void prep(const float* __restrict__ qkv_w,
                                            const float* __restrict__ proj_w,
                                            const float* __restrict__ fcgv_w,
                                            const float* __restrict__ fco_w,
                                            const float* __restrict__ rpb,
                                            short* __restrict__ wbuf,
                                            short* __restrict__ btb) {
  if (blockIdx.x < 216) {
    int t = blockIdx.x * 256 + threadIdx.x;
    int blk = t >> 6, lane = t & 63;
    int g = lane >> 4, h = lane & 15;
    const float* src;
    if (blk < 216) {
      int b2 = blk;
      int ni = b2 % 3; b2 /= 3;
      int wn = b2 & 1; b2 >>= 1;
      int kt = b2 % 6; b2 /= 6;
      int nt = b2;
      src = qkv_w + (size_t)(nt * 96 + wn * 48 + ni * 16 + h) * 192 + kt * 32 + g * 8;
    } else if (blk < 288) {
      int b2 = blk - 216;
      int ni = b2 % 3; b2 /= 3;
      int wn = b2 & 1; b2 >>= 1;
      int kt = b2 % 6; b2 /= 6;
      int nt = b2;
      src = proj_w + (size_t)(nt * 96 + wn * 48 + ni * 16 + h) * 192 + kt * 32 + g * 8;
    } else if (blk < 672) {
      int b2 = blk - 288;
      int gv = b2 & 1; b2 >>= 1;
      int ni = b2 & 1; b2 >>= 1;
      int wn = b2 & 1; b2 >>= 1;
      int kt = b2 % 6; b2 /= 6;
      int nt = b2;
      int r = wn * 32 + ni * 16 + h;
      int row = gv ? (512 + nt * 64 + r) : (nt * 64 + r);
      src = fcgv_w + (size_t)row * 192 + kt * 32 + g * 8;
    } else {
      int b2 = blk - 672;
      int ni = b2 % 3; b2 /= 3;
      int wn = b2 & 1; b2 >>= 1;
      int kt = b2 & 15; b2 >>= 4;
      int nt = b2;
      src = fco_w + (size_t)(nt * 96 + wn * 48 + ni * 16 + h) * 512 + kt * 32 + g * 8;
    }
    *(bh8*)(wbuf + (size_t)blk * 512 + lane * 8) = pack8(src);
  } else {
    int t = (blockIdx.x - 216) * 256 + threadIdx.x;  // 55296
    int lane = t & 63;
    int u = t >> 6;
    int qi = u & 1;
    int c = lane & 31, hi = lane >> 5;
    int w = (u >> 2) / 9 % 4;
    int head = (u >> 2) / 36;
    int q = w * 64 + qi * 32 + c;
    int qterm = (q >> 4) * 39 + (q & 15);
    short o16[16];
#pragma unroll
    for (int r = 0; r < 16; r++) {
      int kk = ((u >> 2) % 9) * 64 + ((u >> 1) & 1) * 32 + (r & 3) + 8 * (r >> 2) + 4 * hi;
      int ky = (kk * 2731) >> 16;
      int kx = kk - ky * 24;
      int idx = ky * 39 + kx + 600 - qterm;
      o16[r] = f2bf(rpb[idx * 6 + head] * 1.4426950408889634f);
    }
    *(bh8*)(btb + (size_t)u * 1024 + lane * 16)     = *(bh8*)&o16[0];
    *(bh8*)(btb + (size_t)u * 1024 + lane * 16 + 8) = *(bh8*)&o16[8];
  }
}

// ---------------- activation convert -> A-fragment layout, with fused iln-final ----------------
__global__ __launch_bounds__(256) void cvt_aff(const float* __restrict__ src,
                                               const float* __restrict__ part,
                                               const float* __restrict__ w,
                                               const float* __restrict__ bias,
                                               short* __restrict__ dst,
                                               float* __restrict__ st) {
  __shared__ float rs[512];
  const int tid = threadIdx.x;
  const int bb = (blockIdx.x >= 1536) ? 1 : 0;
  rs[tid]       = part[(bb * 256 + tid) * 2];
  rs[256 + tid] = part[(bb * 256 + tid) * 2 + 1];
  __syncthreads();
  for (int s = 128; s > 0; s >>= 1) {
    if (tid < s) { rs[tid] += rs[tid + s]; rs[256 + tid] += rs[256 + tid + s]; }
    __syncthreads();
  }
  const float invn = 1.f / 3145728.f;
  float mean = rs[0] * invn;
  float var  = rs[256] * invn - mean * mean;
  float scale = fminf(sqrtf(var + 1e-6f), 2.f);
  if (tid == 0 && (blockIdx.x == 0 || blockIdx.x == 1536)) {
    st[bb * 2] = mean;
    st[bb * 2 + 1] = scale;
  }
  const float isc = 1.f / scale;
  int t = blockIdx.x * 256 + tid;
  int row = t / 24;
  int c0 = (t - row * 24) * 8;
  int mt = row >> 7, wm = (row >> 6) & 1, mi = (row >> 4) & 3, h = row & 15;
  int kt = c0 >> 5, g = (c0 >> 3) & 3;
  int blk = ((mt * 2 + wm) * 4 + mi) * 6 + kt;
  int lane = g * 16 + h;
  const float* sp = src + (size_t)row * 192 + c0;
  fx4 v0 = *(const fx4*)sp;
  fx4 v1 = *(const fx4*)(sp + 4);
  bh8 pk;
#pragma unroll
  for (int j = 0; j < 4; j++) {
    float a = w[c0 + j] * isc;
    pk[j] = f2bf(v0[j] * a + (bias[c0 + j] - mean * a));
  }
#pragma unroll
  for (int j = 0; j < 4; j++) {
    float a = w[c0 + 4 + j] * isc;
    pk[j + 4] = f2bf(v1[j] * a + (bias[c0 + 4 + j] - mean * a));
  }
  *(bh8*)(dst + (size_t)blk * 512 + lane * 8) = pk;
}

// ---------------- QKV GEMM: barrier-free, fragment operands ----------------
__global__ __launch_bounds__(256) void gemm_qkv(const short* __restrict__ xn,
                                                const short* __restrict__ wq,
                                                const float* __restrict__ wb,
                                                short* __restrict__ qb,
                                                short* __restrict__ kb,
                                                short* __restrict__ vb) {
  const int mt = blockIdx.x, by = blockIdx.y;
  const int m0 = mt * 128;
  const int tid = threadIdx.x, wid = tid >> 6, lane = tid & 63;
  const int g = lane >> 4, h = lane & 15;
  const int wm = wid >> 1, wn = wid & 1;
  fx4 acc[4][3];
#pragma unroll
  for (int i = 0; i < 4; i++)
#pragma unroll
    for (int j = 0; j < 3; j++) acc[i][j] = fzero();

#pragma unroll
  for (int kt = 0; kt < 6; kt++) {
    bh8 af[4], bf[3];
#pragma unroll
    for (int mi = 0; mi < 4; mi++)
      af[mi] = *(const bh8*)(xn + (size_t)((((mt * 2 + wm) * 4 + mi) * 6 + kt)) * 512 + lane * 8);
#pragma unroll
    for (int ni = 0; ni < 3; ni++)
      bf[ni] = *(const bh8*)(wq + (size_t)(((by * 6 + kt) * 2 + wn) * 3 + ni) * 512 + lane * 8);
#pragma unroll
    for (int ni = 0; ni < 3; ni++)
#pragma unroll
      for (int mi = 0; mi < 4; mi++) acc[mi][ni] = mfma16(af[mi], bf[ni], acc[mi][ni]);
  }
  const int seg = by >> 1;
  short* dst = (seg == 0) ? qb : (seg == 1 ? kb : vb);
  const float sc = (seg == 1) ? 0.25503486f : 1.0f;  // SCALE * log2(e) folded into K
  const int colbase = (by & 1) * 96;
#pragma unroll
  for (int mi = 0; mi < 4; mi++)
#pragma unroll
    for (int ni = 0; ni < 3; ni++)
#pragma unroll
      for (int r = 0; r < 4; r++) {
        int row = m0 + wm * 64 + mi * 16 + g * 4 + r;
        int col = colbase + wn * 48 + ni * 16 + h;
        dst[(size_t)row * 192 + col] = f2bf((acc[mi][ni][r] + wb[seg * 192 + col]) * sc);
      }
}

// ---------------- attention: full-window, single-buffer, bf16 bias table, setprio ----------------
__global__ __launch_bounds__(256, 3) void attn_kernel(const short* __restrict__ qb,
                                                      const short* __restrict__ kb,
                                                      const short* __restrict__ vb,
                                                      const short* __restrict__ btb,
                                                      short* __restrict__ ao) {
  __shared__ short K_lds[64 * 40];
  __shared__ short Vt_lds[32 * 72];
  __shared__ float l_lds[256];
  const int tid = threadIdx.x;
  const int win = blockIdx.x, head = blockIdx.y;
  const int b = win >> 6, wy = (win >> 3) & 7, wx = win & 7;
  const int w = tid >> 6, lane = tid & 63, c = lane & 31, hi = lane >> 5;

  bh8 qf[2][2];
#pragma unroll
  for (int qi = 0; qi < 2; qi++) {
    int ql = w * 64 + qi * 32 + c;
    size_t gl = (size_t)(b * 16384 + (wy * 16 + (ql >> 4)) * 128 + wx * 16 + (ql & 15));
#pragma unroll
    for (int ds = 0; ds < 2; ds++)
      qf[qi][ds] = *(const bh8*)(qb + gl * 192 + head * 32 + ds * 16 + hi * 8);
  }
  float l_run[2] = {0.f, 0.f};
  fx16 out[2];
#pragma unroll
  for (int r = 0; r < 16; r++) { out[0][r] = 0.f; out[1][r] = 0.f; }

  const int hw9 = (head * 4 + w) * 9;

  const int kl_a = tid >> 2, part_a = tid & 3;
  const int kl_b = tid & 63, hg_b = tid >> 6;

  for (int kc = 0; kc < 9; kc++) {
    __syncthreads();
    {
      int key = kc * 64 + kl_a;
      int ky = key / 24, kx = key - ky * 24;
      int py = wy * 16 - 4 + ky, px = wx * 16 - 4 + kx;
      bh8 kv = {};
      if ((unsigned)py < 128u && (unsigned)px < 128u)
        kv = *(const bh8*)(kb + ((size_t)(b * 16384 + py * 128 + px)) * 192 + head * 32 + part_a * 8);
      *(bh8*)&K_lds[kl_a * 40 + part_a * 8] = kv;

      int key2 = kc * 64 + kl_b;
      int ky2 = key2 / 24, kx2 = key2 - ky2 * 24;
      int py2 = wy * 16 - 4 + ky2, px2 = wx * 16 - 4 + kx2;
      bh8 vv = {};
      if ((unsigned)py2 < 128u && (unsigned)px2 < 128u)
        vv = *(const bh8*)(vb + ((size_t)(b * 16384 + py2 * 128 + px2)) * 192 + head * 32 + hg_b * 8);
#pragma unroll
      for (int j = 0; j < 8; j++) Vt_lds[(hg_b * 8 + j) * 72 + kl_b] = vv[j];
    }
    __syncthreads();

    const short* base_kc = btb + (size_t)(hw9 + kc) * 4096 + lane * 16;
#pragma unroll
    for (int ki = 0; ki < 2; ki++) {
      fx16 st[2];
#pragma unroll
      for (int qi = 0; qi < 2; qi++) {
        const short* bp = base_kc + (ki * 2 + qi) * 1024;
        int4 b0 = *(const int4*)bp;
        int4 b1 = *(const int4*)(bp + 8);
#pragma unroll
        for (int d = 0; d < 4; d++) {
          unsigned u0 = ((const unsigned*)&b0)[d];
          unsigned u1 = ((const unsigned*)&b1)[d];
          st[qi][2 * d]     = __builtin_bit_cast(float, u0 << 16);
          st[qi][2 * d + 1] = __builtin_bit_cast(float, u0 & 0xffff0000u);
          st[qi][8 + 2 * d]     = __builtin_bit_cast(float, u1 << 16);
          st[qi][8 + 2 * d + 1] = __builtin_bit_cast(float, u1 & 0xffff0000u);
        }
      }
      __builtin_amdgcn_s_setprio(1);
#pragma unroll
      for (int ds = 0; ds < 2; ds++) {
        bh8 kf = *(bh8*)&K_lds[(ki * 32 + c) * 40 + ds * 16 + hi * 8];
        st[0] = mfma32(kf, qf[0][ds], st[0]);
        st[1] = mfma32(kf, qf[1][ds], st[1]);
      }
      __builtin_amdgcn_s_setprio(0);
#pragma unroll
      for (int qi = 0; qi < 2; qi++) {
        float s = 0.f;
#pragma unroll
        for (int r = 0; r < 16; r++) {
          float p = fexp2(st[qi][r]);
          st[qi][r] = p;
          s += p;
        }
        l_run[qi] += s;
      }
      int dwq[2][2][4];
#pragma unroll
      for (int qi = 0; qi < 2; qi++)
#pragma unroll
        for (int k1 = 0; k1 < 2; k1++)
#pragma unroll
          for (int p01 = 0; p01 < 2; p01++) {
            int rA = 2 * p01 + 8 * k1;
            int A, Bv;
            asm("v_cvt_pk_bf16_f32 %0, %1, %2" : "=v"(A)  : "v"(st[qi][rA]),     "v"(st[qi][rA + 1]));
            asm("v_cvt_pk_bf16_f32 %0, %1, %2" : "=v"(Bv) : "v"(st[qi][rA + 4]), "v"(st[qi][rA + 5]));
#if __has_builtin(__builtin_amdgcn_permlane32_swap)
            auto pr = __builtin_amdgcn_permlane32_swap((unsigned)A, (unsigned)Bv, false, false);
            dwq[qi][k1][p01]     = (int)pr[0];
            dwq[qi][k1][p01 + 2] = (int)pr[1];
#else
            int Ax = __shfl_xor(A, 32);
            int Bx = __shfl_xor(Bv, 32);
            dwq[qi][k1][p01]     = hi ? Bx : A;
            dwq[qi][k1][p01 + 2] = hi ? Bv : Ax;
#endif
          }
      __builtin_amdgcn_s_setprio(1);
#pragma unroll
      for (int k1 = 0; k1 < 2; k1++) {
        bh8 bv2 = *(bh8*)&Vt_lds[c * 72 + (ki * 2 + k1) * 16 + hi * 8];
#pragma unroll
        for (int qi = 0; qi < 2; qi++) {
          int4 t4 = {dwq[qi][k1][0], dwq[qi][k1][1], dwq[qi][k1][2], dwq[qi][k1][3]};
          out[qi] = mfma32(__builtin_bit_cast(bh8, t4), bv2, out[qi]);
        }
      }
      __builtin_amdgcn_s_setprio(0);
    }
  }
#pragma unroll
  for (int qi = 0; qi < 2; qi++) {
    float lp = l_run[qi] + __shfl_xor(l_run[qi], 32);
    l_lds[w * 64 + qi * 32 + c] = 1.f / lp;
  }
  __syncthreads();
#pragma unroll
  for (int qi = 0; qi < 2; qi++)
#pragma unroll
    for (int r = 0; r < 16; r++) {
      int row = (r & 3) + 8 * (r >> 2) + 4 * hi;
      float val = out[qi][r] * l_lds[w * 64 + qi * 32 + row];
      int ql = w * 64 + qi * 32 + row;
      ao[((size_t)(win * 256 + ql)) * 192 + head * 32 + c] = f2bf(val);
    }
}

// ---------------- proj GEMM: A direct from ao (L2), B fragments; barrier-free loop ----------------
__global__ __launch_bounds__(256) void gemm_proj(const short* __restrict__ ao,
                                                 const short* __restrict__ wp,
                                                 const float* __restrict__ wb,
                                                 const float* __restrict__ x,
                                                 const float* __restrict__ ls1,
                                                 const float* __restrict__ st,
                                                 float* __restrict__ x1,
                                                 float* __restrict__ part2) {
  __shared__ float red[512];
  const int m0 = blockIdx.x * 128, by = blockIdx.y;
  const int tid = threadIdx.x, wid = tid >> 6, lane = tid & 63;
  const int g = lane >> 4, h = lane & 15;
  const int wm = wid >> 1, wn = wid & 1;
  fx4 acc[4][3];
#pragma unroll
  for (int i = 0; i < 4; i++)
#pragma unroll
    for (int j = 0; j < 3; j++) acc[i][j] = fzero();

#pragma unroll
  for (int kt = 0; kt < 6; kt++) {
    bh8 af[4], bf[3];
#pragma unroll
    for (int mi = 0; mi < 4; mi++)
      af[mi] = *(const bh8*)(ao + (size_t)(m0 + wm * 64 + mi * 16 + h) * 192 + kt * 32 + g * 8);
#pragma unroll
    for (int ni = 0; ni < 3; ni++)
      bf[ni] = *(const bh8*)(wp + (size_t)(((by * 6 + kt) * 2 + wn) * 3 + ni) * 512 + lane * 8);
#pragma unroll
    for (int ni = 0; ni < 3; ni++)
#pragma unroll
      for (int mi = 0; mi < 4; mi++) acc[mi][ni] = mfma16(af[mi], bf[ni], acc[mi][ni]);
  }
  const int n0 = by * 96;
  float ps = 0.f, ps2 = 0.f;
#pragma unroll
  for (int mi = 0; mi < 4; mi++)
#pragma unroll
    for (int ni = 0; ni < 3; ni++)
#pragma unroll
      for (int r = 0; r < 4; r++) {
        int grow = m0 + wm * 64 + mi * 16 + g * 4 + r;
        int win = grow >> 8, q = grow & 255;
        int bb = win >> 6, wy = (win >> 3) & 7, wxx = win & 7;
        int l = (wy * 16 + (q >> 4)) * 128 + wxx * 16 + (q & 15);
        int col = n0 + wn * 48 + ni * 16 + h;
        size_t di = ((size_t)(bb * 16384 + l)) * 192 + col;
        float s1 = st[bb * 2 + 1];
        float val = x[di] + s1 * ls1[col] * (acc[mi][ni][r] + wb[col]);
        x1[di] = val;
        ps += val;
        ps2 += val * val;
      }
  red[tid] = ps; red[256 + tid] = ps2;
  __syncthreads();
  for (int s = 128; s > 0; s >>= 1) {
    if (tid < s) { red[tid] += red[tid + s]; red[256 + tid] += red[256 + tid + s]; }
    __syncthreads();
  }
  if (tid == 0) {
    int pi = blockIdx.x * 2 + by;
    part2[pi * 2] = red[0];
    part2[pi * 2 + 1] = red[256];
  }
}

// ---------------- fcgv GEMM: barrier-free fragment loop + SiLU -> planar hp ----------------
__global__ __launch_bounds__(256) void gemm_fcgv(const short* __restrict__ x1n,
                                                 const short* __restrict__ wg,
                                                 const float* __restrict__ wb,
                                                 short* __restrict__ hp) {
  __shared__ short T[64 * 136];
  const int mt = blockIdx.x, by = blockIdx.y, n0 = by * 64;
  const int m0 = mt * 128;
  const int b = m0 >> 14, l0 = m0 & 16383;
  const int tid = threadIdx.x, wid = tid >> 6, lane = tid & 63;
  const int g = lane >> 4, h = lane & 15;
  const int wm = wid >> 1, wn = wid & 1;
  fx4 accg[4][2], accv[4][2];
#pragma unroll
  for (int i = 0; i < 4; i++)
#pragma unroll
    for (int j = 0; j < 2; j++) { accg[i][j] = fzero(); accv[i][j] = fzero(); }

#pragma unroll
  for (int kt = 0; kt < 6; kt++) {
    bh8 af[4], bg[2], bv[2];
#pragma unroll
    for (int mi = 0; mi < 4; mi++)
      af[mi] = *(const bh8*)(x1n + (size_t)((((mt * 2 + wm) * 4 + mi) * 6 + kt)) * 512 + lane * 8);
#pragma unroll
    for (int ni = 0; ni < 2; ni++) {
      size_t base = (size_t)((((by * 6 + kt) * 2 + wn) * 2 + ni) * 2) * 512;
      bg[ni] = *(const bh8*)(wg + base + lane * 8);
      bv[ni] = *(const bh8*)(wg + base + 512 + lane * 8);
    }
#pragma unroll
    for (int ni = 0; ni < 2; ni++)
#pragma unroll
      for (int mi = 0; mi < 4; mi++) {
        accg[mi][ni] = mfma16(af[mi], bg[ni], accg[mi][ni]);
        accv[mi][ni] = mfma16(af[mi], bv[ni], accv[mi][ni]);
      }
  }
  short hs[4][2][4];
#pragma unroll
  for (int mi = 0; mi < 4; mi++)
#pragma unroll
    for (int ni = 0; ni < 2; ni++)
#pragma unroll
      for (int r = 0; r < 4; r++) {
        int colg = n0 + wn * 32 + ni * 16 + h;
        float gv = accg[mi][ni][r] + wb[colg];
        float vv = accv[mi][ni][r] + wb[512 + colg];
        hs[mi][ni][r] = f2bf(gv / (1.f + __expf(-gv)) * vv);
      }
#pragma unroll
  for (int mi = 0; mi < 4; mi++)
#pragma unroll
    for (int ni = 0; ni < 2; ni++)
#pragma unroll
      for (int r = 0; r < 4; r++) {
        int cc = wn * 32 + ni * 16 + h;
        int rl = wm * 64 + mi * 16 + g * 4 + r;
        T[cc * 136 + rl] = hs[mi][ni][r];
      }
  __syncthreads();
#pragma unroll
  for (int i = 0; i < 4; i++) {
    int ch = tid + i * 256;
    int cc = ch >> 4, lg = ch & 15;
    bh8 v = *(bh8*)&T[cc * 136 + lg * 8];
    *(bh8*)(hp + (((size_t)(b * 512 + n0 + cc)) << 14) + l0 + lg * 8) = v;
  }
}

// ---------------- fused depthwise convs: 64-row stripes, out-of-place ----------------
__global__ __launch_bounds__(256) void dw_fused(const short* __restrict__ in,
                                                const float* __restrict__ w1,
                                                const float* __restrict__ b1,
                                                const float* __restrict__ w2,
                                                const float* __restrict__ b2,
                                                const float* __restrict__ dsc,
                                                short* __restrict__ outp) {
  __shared__ short P[70 * 136];
  __shared__ short D[68 * 136];
  const int p = blockIdx.x >> 1, s = blockIdx.x & 1, c = p & 511;
  const int tid = threadIdx.x;
  const int r0 = s * 64;
  const int plo = s ? 61 : 0;
  const int pbase = r0 - 3;
  const int dlo = s ? 62 : 0;
  const int dbase = r0 - 2;
  const short* ip = in + ((size_t)p << 14);

  for (int i = tid; i < 67 * 16; i += 256) {
    int rr = plo + (i >> 4), sl = i & 15;
    bh8 v = *(const bh8*)(ip + rr * 128 + sl * 8);
    *(bh8*)&P[(rr - pbase) * 136 + sl * 8] = v;
  }
  float k1[9], k2[9];
#pragma unroll
  for (int j = 0; j < 9; j++) { k1[j] = w1[c * 9 + j]; k2[j] = w2[c * 9 + j]; }
  const float bias1 = b1[c], bias2 = b2[c], ds = dsc[0];
  __syncthreads();

  for (int i = tid; i < 66 * 16; i += 256) {
    int gy = dlo + (i >> 4);
    int x0 = (i & 15) * 8;
    float acc[8];
#pragma unroll
    for (int q = 0; q < 8; q++) acc[q] = bias1;
#pragma unroll
    for (int ky = 0; ky < 3; ky++) {
      int yy = gy + ky - 1;
      if ((unsigned)yy < 128u) {
        const short* row = &P[(yy - pbase) * 136];
        float f[10];
        bh8 v = *(const bh8*)&row[x0];
#pragma unroll
        for (int j = 0; j < 8; j++) f[j + 1] = bf2f(v[j]);
        f[0] = (x0 == 0) ? 0.f : bf2f(row[x0 - 1]);
        f[9] = (x0 == 120) ? 0.f : bf2f(row[x0 + 8]);
        float w0 = k1[ky * 3], wA = k1[ky * 3 + 1], wB = k1[ky * 3 + 2];
#pragma unroll
        for (int q = 0; q < 8; q++) acc[q] += f[q] * w0 + f[q + 1] * wA + f[q + 2] * wB;
      }
    }
    bh8 pk;
#pragma unroll
    for (int q = 0; q < 8; q++) pk[q] = f2bf(acc[q]);
    *(bh8*)&D[(gy - dbase) * 136 + x0] = pk;
  }
  __syncthreads();

  for (int i = tid; i < 64 * 16; i += 256) {
    int gy = r0 + (i >> 4);
    int x0 = (i & 15) * 8;
    float acc[8], center[8];
#pragma unroll
    for (int q = 0; q < 8; q++) acc[q] = bias2;
#pragma unroll
    for (int ky = 0; ky < 3; ky++) {
      int yy = gy + (ky - 1) * 2;
      if ((unsigned)yy < 128u) {
        const short* row = &D[(yy - dbase) * 136];
        float f[12];
        bh8 v = *(const bh8*)&row[x0];
#pragma unroll
        for (int j = 0; j < 8; j++) f[j + 2] = bf2f(v[j]);
        if (x0 == 0) { f[0] = 0.f; f[1] = 0.f; }
        else {
          unsigned lp = *(const unsigned*)&row[x0 - 2];
          f[0] = __builtin_bit_cast(float, lp << 16);
          f[1] = __builtin_bit_cast(float, lp & 0xffff0000u);
        }
        if (x0 == 120) { f[10] = 0.f; f[11] = 0.f; }
        else {
          unsigned rp = *(const unsigned*)&row[x0 + 8];
          f[10] = __builtin_bit_cast(float, rp << 16);
          f[11] = __builtin_bit_cast(float, rp & 0xffff0000u);
        }
        float w0 = k2[ky * 3], wA = k2[ky * 3 + 1], wB = k2[ky * 3 + 2];
#pragma unroll
        for (int q = 0; q < 8; q++) acc[q] += f[q] * w0 + f[q + 2] * wA + f[q + 4] * wB;
        if (ky == 1) {
#pragma unroll
          for (int q = 0; q < 8; q++) center[q] = f[q + 2];
        }
      }
    }
    bh8 pk;
#pragma unroll
    for (int q = 0; q < 8; q++) pk[q] = f2bf(center[q] + ds * acc[q]);
    *(bh8*)(outp + ((size_t)p << 14) + gy * 128 + x0) = pk;
  }
}

// ---------------- fco GEMM: A via LDS transpose, B fragments ----------------
__global__ __launch_bounds__(256) void gemm_fco(const short* __restrict__ h2,
                                                const short* __restrict__ wo,
                                                const float* __restrict__ wb,
                                                const float* __restrict__ x1,
                                                const float* __restrict__ ls2,
                                                const float* __restrict__ st,
                                                float* __restrict__ out) {
  __shared__ short As[128 * 40];
  const int m0 = blockIdx.x * 128, by = blockIdx.y, n0 = by * 96;
  const int b = m0 >> 14, l0 = m0 & 16383;
  const int tid = threadIdx.x, wid = tid >> 6, lane = tid & 63;
  const int g = lane >> 4, h = lane & 15;
  const int wm = wid >> 1, wn = wid & 1;
  const int cp = tid & 15, lg = tid >> 4;
  fx4 acc[4][3];
#pragma unroll
  for (int i = 0; i < 4; i++)
#pragma unroll
    for (int j = 0; j < 3; j++) acc[i][j] = fzero();

  for (int kt = 0; kt < 16; kt++) {
    const int k0 = kt * 32;
    {
      const short* basep = h2 + (((size_t)(b * 512 + k0 + 2 * cp)) << 14) + l0 + lg * 8;
      bh8 v0 = *(const bh8*)basep;
      bh8 v1 = *(const bh8*)(basep + 16384);
#pragma unroll
      for (int j = 0; j < 8; j++) {
        unsigned pkv = (unsigned)(unsigned short)v0[j] | (((unsigned)(unsigned short)v1[j]) << 16);
        *(unsigned*)&As[(lg * 8 + j) * 40 + 2 * cp] = pkv;
      }
    }
    __syncthreads();
    bh8 af[4], bf[3];
#pragma unroll
    for (int mi = 0; mi < 4; mi++)
      af[mi] = *(bh8*)&As[(wm * 64 + mi * 16 + h) * 40 + g * 8];
#pragma unroll
    for (int ni = 0; ni < 3; ni++)
      bf[ni] = *(const bh8*)(wo + (size_t)(((by * 16 + kt) * 2 + wn) * 3 + ni) * 512 + lane * 8);
#pragma unroll
    for (int ni = 0; ni < 3; ni++)
#pragma unroll
      for (int mi = 0; mi < 4; mi++) acc[mi][ni] = mfma16(af[mi], bf[ni], acc[mi][ni]);
    __syncthreads();
  }
  float s2 = st[b * 2 + 1];
#pragma unroll
  for (int mi = 0; mi < 4; mi++)
#pragma unroll
    for (int ni = 0; ni < 3; ni++)
#pragma unroll
      for (int r = 0; r < 4; r++) {
        int row = m0 + wm * 64 + mi * 16 + g * 4 + r;
        int col = n0 + wn * 48 + ni * 16 + h;
        size_t di = (size_t)row * 192 + col;
        out[di] = x1[di] + s2 * ls2[col] * (acc[mi][ni][r] + wb[col]);
      }
}

extern "C" void kernel_launch(void* const* d_in, const int* in_sizes, int n_in,
                              void* d_out, int out_size, void* d_ws, size_t ws_size,
                              hipStream_t stream) {
  const float* x      = (const float*)d_in[0];
  const float* qkv_w  = (const float*)d_in[1];
  const float* qkv_b  = (const float*)d_in[2];
  const float* proj_w = (const float*)d_in[3];
  const float* proj_b = (const float*)d_in[4];
  const float* rpb    = (const float*)d_in[5];
  const float* n1_w   = (const float*)d_in[6];
  const float* n1_b   = (const float*)d_in[7];
  const float* ls1    = (const float*)d_in[8];
  const float* n2_w   = (const float*)d_in[9];
  const float* n2_b   = (const float*)d_in[10];
  const float* ls2    = (const float*)d_in[11];
  const float* fcgv_w = (const float*)d_in[12];
  const float* fcgv_b = (const float*)d_in[13];
  const float* dw_w   = (const float*)d_in[14];
  const float* dw_b   = (const float*)d_in[15];
  const float* dwd_w  = (const float*)d_in[16];
  const float* dwd_b  = (const float*)d_in[17];
  const float* dil    = (const float*)d_in[18];
  const float* fco_w  = (const float*)d_in[19];
  const float* fco_b  = (const float*)d_in[20];
  float* out = (float*)d_out;
  char* ws = (char*)d_ws;

  // workspace layout (bytes); peak ~104.5 MB
  short* wbuf = (short*)(ws + 0);
  short* wq = wbuf;
  short* wp = wbuf + 110592;
  short* wg = wbuf + 147456;
  short* wo = wbuf + 344064;
  float* part  = (float*)(ws + 884736);
  float* st1   = (float*)(ws + 891904);
  float* st2   = (float*)(ws + 891968);
  float* part2 = (float*)(ws + 892032);
  short* xn  = (short*)(ws + 1048576);
  short* btb = (short*)(ws + 13631488);
  short* qb  = (short*)(ws + 17301504);
  short* kb  = (short*)(ws + 29884416);
  short* vb  = (short*)(ws + 42467328);
  short* ao  = (short*)(ws + 55050240);
  float* x1  = (float*)(ws + 1048576);
  short* x1n = (short*)(ws + 26214400);
  short* hp  = (short*)(ws + 42467328);
  short* h2  = (short*)(ws + 76021760);

  iln_partial<<<512, 256, 0, stream>>>(x, part);
  prep<<<432, 256, 0, stream>>>(qkv_w, proj_w, fcgv_w, fco_w, rpb, wbuf, btb);
  cvt_aff<<<3072, 256, 0, stream>>>(x, part, n1_w, n1_b, xn, st1);
  gemm_qkv<<<dim3(256, 6), 256, 0, stream>>>(xn, wq, qkv_b, qb, kb, vb);
  attn_kernel<<<dim3(128, 6), 256, 0, stream>>>(qb, kb, vb, btb, ao);
  gemm_proj<<<dim3(256, 2), 256, 0, stream>>>(ao, wp, proj_b, x, ls1, st1, x1, part2);
  cvt_aff<<<3072, 256, 0, stream>>>(x1, part2, n2_w, n2_b, x1n, st2);
  gemm_fcgv<<<dim3(256, 8), 256, 0, stream>>>(x1n, wg, fcgv_b, hp);
  dw_fused<<<2048, 256, 0, stream>>>(hp, dw_w, dw_b, dwd_w, dwd_b, dil, h2);
  gemm_fco<<<dim3(256, 2), 256, 0, stream>>>(h2, wo, fco_b, x1, ls2, st2, out);
}

// Round 16
// 169.795 us; speedup vs baseline: 1.0826x; 1.0210x over previous
//
#include <hip/hip_runtime.h>

#define DI __device__ __forceinline__

typedef __attribute__((ext_vector_type(8))) short bh8;
typedef __attribute__((ext_vector_type(4))) float fx4;
typedef __attribute__((ext_vector_type(16))) float fx16;

DI short f2bf(float f) {
  unsigned u = __builtin_bit_cast(unsigned, f);
  u += 0x7FFFu + ((u >> 16) & 1u);
  return (short)(u >> 16);
}
DI float bf2f(short s) {
  unsigned u = ((unsigned)(unsigned short)s) << 16;
  return __builtin_bit_cast(float, u);
}
DI fx4 mfma16(bh8 a, bh8 b, fx4 c) {
  return __builtin_amdgcn_mfma_f32_16x16x32_bf16(a, b, c, 0, 0, 0);
}
DI fx16 mfma32(bh8 a, bh8 b, fx16 c) {
  return __builtin_amdgcn_mfma_f32_32x32x16_bf16(a, b, c, 0, 0, 0);
}
DI fx4 fzero() { fx4 z = {0.f, 0.f, 0.f, 0.f}; return z; }

DI float fexp2(float x) {
#if __has_builtin(__builtin_amdgcn_exp2f)
  return __builtin_amdgcn_exp2f(x);
#else
  return exp2f(x);
#endif
}

DI bh8 pack8(const float* src) {
  fx4 v0 = *(const fx4*)src;
  fx4 v1 = *(const fx4*)(src + 4);
  bh8 pk;
#pragma unroll
  for (int j = 0; j < 4; j++) { pk[j] = f2bf(v0[j]); pk[j + 4] = f2bf(v1[j]); }
  return pk;
}

// ---------------- holistic LN stats (partials over x) ----------------
__global__ __launch_bounds__(256) void iln_partial(const float* __restrict__ x,
                                                   float* __restrict__ part) {
  const int blk = blockIdx.x, tid = threadIdx.x;
  const fx4* p = (const fx4*)(x + (size_t)blk * 12288);
  float s = 0.f, s2 = 0.f;
#pragma unroll
  for (int i = 0; i < 12; i++) {
    fx4 v = p[i * 256 + tid];
    s  += v[0] + v[1] + v[2] + v[3];
    s2 += v[0] * v[0] + v[1] * v[1] + v[2] * v[2] + v[3] * v[3];
  }
  __shared__ float sm[512];
  sm[tid] = s; sm[256 + tid] = s2;
  __syncthreads();
  for (int st = 128; st > 0; st >>= 1) {
    if (tid < st) { sm[tid] += sm[tid + st]; sm[256 + tid] += sm[256 + tid + st]; }
    __syncthreads();
  }
  if (tid == 0) { part[blk * 2] = sm[0]; part[blk * 2 + 1] = sm[256]; }
}

// ---------------- prep: weight convert (fragment layout) + bf16 bias table ----------------
__global__ __launch_bounds__(256) void prep(const float* __restrict__ qkv_w,
                                            const float* __restrict__ proj_w,
                                            const float* __restrict__ fcgv_w,
                                            const float* __restrict__ fco_w,
                                            const float* __restrict__ rpb,
                                            short* __restrict__ wbuf,
                                            short* __restrict__ btb) {
  if (blockIdx.x < 216) {
    int t = blockIdx.x * 256 + threadIdx.x;
    int blk = t >> 6, lane = t & 63;
    int g = lane >> 4, h = lane & 15;
    const float* src;
    if (blk < 216) {
      int b2 = blk;
      int ni = b2 % 3; b2 /= 3;
      int wn = b2 & 1; b2 >>= 1;
      int kt = b2 % 6; b2 /= 6;
      int nt = b2;
      src = qkv_w + (size_t)(nt * 96 + wn * 48 + ni * 16 + h) * 192 + kt * 32 + g * 8;
    } else if (blk < 288) {
      int b2 = blk - 216;
      int ni = b2 % 3; b2 /= 3;
      int wn = b2 & 1; b2 >>= 1;
      int kt = b2 % 6; b2 /= 6;
      int nt = b2;
      src = proj_w + (size_t)(nt * 96 + wn * 48 + ni * 16 + h) * 192 + kt * 32 + g * 8;
    } else if (blk < 672) {
      int b2 = blk - 288;
      int gv = b2 & 1; b2 >>= 1;
      int ni = b2 & 1; b2 >>= 1;
      int wn = b2 & 1; b2 >>= 1;
      int kt = b2 % 6; b2 /= 6;
      int nt = b2;
      int r = wn * 32 + ni * 16 + h;
      int row = gv ? (512 + nt * 64 + r) : (nt * 64 + r);
      src = fcgv_w + (size_t)row * 192 + kt * 32 + g * 8;
    } else {
      int b2 = blk - 672;
      int ni = b2 % 3; b2 /= 3;
      int wn = b2 & 1; b2 >>= 1;
      int kt = b2 & 15; b2 >>= 4;
      int nt = b2;
      src = fco_w + (size_t)(nt * 96 + wn * 48 + ni * 16 + h) * 512 + kt * 32 + g * 8;
    }
    *(bh8*)(wbuf + (size_t)blk * 512 + lane * 8) = pack8(src);
  } else {
    int t = (blockIdx.x - 216) * 256 + threadIdx.x;  // 55296
    int lane = t & 63;
    int u = t >> 6;
    int qi = u & 1;
    int c = lane & 31, hi = lane >> 5;
    int w = (u >> 2) / 9 % 4;
    int head = (u >> 2) / 36;
    int q = w * 64 + qi * 32 + c;
    int qterm = (q >> 4) * 39 + (q & 15);
    short o16[16];
#pragma unroll
    for (int r = 0; r < 16; r++) {
      int kk = ((u >> 2) % 9) * 64 + ((u >> 1) & 1) * 32 + (r & 3) + 8 * (r >> 2) + 4 * hi;
      int ky = (kk * 2731) >> 16;
      int kx = kk - ky * 24;
      int idx = ky * 39 + kx + 600 - qterm;
      o16[r] = f2bf(rpb[idx * 6 + head] * 1.4426950408889634f);
    }
    *(bh8*)(btb + (size_t)u * 1024 + lane * 16)     = *(bh8*)&o16[0];
    *(bh8*)(btb + (size_t)u * 1024 + lane * 16 + 8) = *(bh8*)&o16[8];
  }
}

// ---------------- activation convert (fp32 src) -> A-fragment layout, fused iln-final ----------------
__global__ __launch_bounds__(256) void cvt_aff(const float* __restrict__ src,
                                               const float* __restrict__ part,
                                               const float* __restrict__ w,
                                               const float* __restrict__ bias,
                                               short* __restrict__ dst,
                                               float* __restrict__ st) {
  __shared__ float rs[512];
  const int tid = threadIdx.x;
  const int bb = (blockIdx.x >= 1536) ? 1 : 0;
  rs[tid]       = part[(bb * 256 + tid) * 2];
  rs[256 + tid] = part[(bb * 256 + tid) * 2 + 1];
  __syncthreads();
  for (int s = 128; s > 0; s >>= 1) {
    if (tid < s) { rs[tid] += rs[tid + s]; rs[256 + tid] += rs[256 + tid + s]; }
    __syncthreads();
  }
  const float invn = 1.f / 3145728.f;
  float mean = rs[0] * invn;
  float var  = rs[256] * invn - mean * mean;
  float scale = fminf(sqrtf(var + 1e-6f), 2.f);
  if (tid == 0 && (blockIdx.x == 0 || blockIdx.x == 1536)) {
    st[bb * 2] = mean;
    st[bb * 2 + 1] = scale;
  }
  const float isc = 1.f / scale;
  int t = blockIdx.x * 256 + tid;
  int row = t / 24;
  int c0 = (t - row * 24) * 8;
  int mt = row >> 7, wm = (row >> 6) & 1, mi = (row >> 4) & 3, h = row & 15;
  int kt = c0 >> 5, g = (c0 >> 3) & 3;
  int blk = ((mt * 2 + wm) * 4 + mi) * 6 + kt;
  int lane = g * 16 + h;
  const float* sp = src + (size_t)row * 192 + c0;
  fx4 v0 = *(const fx4*)sp;
  fx4 v1 = *(const fx4*)(sp + 4);
  bh8 pk;
#pragma unroll
  for (int j = 0; j < 4; j++) {
    float a = w[c0 + j] * isc;
    pk[j] = f2bf(v0[j] * a + (bias[c0 + j] - mean * a));
  }
#pragma unroll
  for (int j = 0; j < 4; j++) {
    float a = w[c0 + 4 + j] * isc;
    pk[j + 4] = f2bf(v1[j] * a + (bias[c0 + 4 + j] - mean * a));
  }
  *(bh8*)(dst + (size_t)blk * 512 + lane * 8) = pk;
}

// ---------------- activation convert (bf16 src) -> A-fragment layout, fused iln-final ----------------
__global__ __launch_bounds__(256) void cvt_affb(const short* __restrict__ src,
                                                const float* __restrict__ part,
                                                const float* __restrict__ w,
                                                const float* __restrict__ bias,
                                                short* __restrict__ dst,
                                                float* __restrict__ st) {
  __shared__ float rs[512];
  const int tid = threadIdx.x;
  const int bb = (blockIdx.x >= 1536) ? 1 : 0;
  rs[tid]       = part[(bb * 256 + tid) * 2];
  rs[256 + tid] = part[(bb * 256 + tid) * 2 + 1];
  __syncthreads();
  for (int s = 128; s > 0; s >>= 1) {
    if (tid < s) { rs[tid] += rs[tid + s]; rs[256 + tid] += rs[256 + tid + s]; }
    __syncthreads();
  }
  const float invn = 1.f / 3145728.f;
  float mean = rs[0] * invn;
  float var  = rs[256] * invn - mean * mean;
  float scale = fminf(sqrtf(var + 1e-6f), 2.f);
  if (tid == 0 && (blockIdx.x == 0 || blockIdx.x == 1536)) {
    st[bb * 2] = mean;
    st[bb * 2 + 1] = scale;
  }
  const float isc = 1.f / scale;
  int t = blockIdx.x * 256 + tid;
  int row = t / 24;
  int c0 = (t - row * 24) * 8;
  int mt = row >> 7, wm = (row >> 6) & 1, mi = (row >> 4) & 3, h = row & 15;
  int kt = c0 >> 5, g = (c0 >> 3) & 3;
  int blk = ((mt * 2 + wm) * 4 + mi) * 6 + kt;
  int lane = g * 16 + h;
  bh8 v = *(const bh8*)(src + (size_t)row * 192 + c0);
  bh8 pk;
#pragma unroll
  for (int j = 0; j < 8; j++) {
    float a = w[c0 + j] * isc;
    pk[j] = f2bf(bf2f(v[j]) * a + (bias[c0 + j] - mean * a));
  }
  *(bh8*)(dst + (size_t)blk * 512 + lane * 8) = pk;
}

// ---------------- QKV GEMM: barrier-free, fragment operands ----------------
__global__ __launch_bounds__(256) void gemm_qkv(const short* __restrict__ xn,
                                                const short* __restrict__ wq,
                                                const float* __restrict__ wb,
                                                short* __restrict__ qb,
                                                short* __restrict__ kb,
                                                short* __restrict__ vb) {
  const int mt = blockIdx.x, by = blockIdx.y;
  const int m0 = mt * 128;
  const int tid = threadIdx.x, wid = tid >> 6, lane = tid & 63;
  const int g = lane >> 4, h = lane & 15;
  const int wm = wid >> 1, wn = wid & 1;
  fx4 acc[4][3];
#pragma unroll
  for (int i = 0; i < 4; i++)
#pragma unroll
    for (int j = 0; j < 3; j++) acc[i][j] = fzero();

#pragma unroll
  for (int kt = 0; kt < 6; kt++) {
    bh8 af[4], bf[3];
#pragma unroll
    for (int mi = 0; mi < 4; mi++)
      af[mi] = *(const bh8*)(xn + (size_t)((((mt * 2 + wm) * 4 + mi) * 6 + kt)) * 512 + lane * 8);
#pragma unroll
    for (int ni = 0; ni < 3; ni++)
      bf[ni] = *(const bh8*)(wq + (size_t)(((by * 6 + kt) * 2 + wn) * 3 + ni) * 512 + lane * 8);
#pragma unroll
    for (int ni = 0; ni < 3; ni++)
#pragma unroll
      for (int mi = 0; mi < 4; mi++) acc[mi][ni] = mfma16(af[mi], bf[ni], acc[mi][ni]);
  }
  const int seg = by >> 1;
  short* dst = (seg == 0) ? qb : (seg == 1 ? kb : vb);
  const float sc = (seg == 1) ? 0.25503486f : 1.0f;  // SCALE * log2(e) folded into K
  const int colbase = (by & 1) * 96;
#pragma unroll
  for (int mi = 0; mi < 4; mi++)
#pragma unroll
    for (int ni = 0; ni < 3; ni++)
#pragma unroll
      for (int r = 0; r < 4; r++) {
        int row = m0 + wm * 64 + mi * 16 + g * 4 + r;
        int col = colbase + wn * 48 + ni * 16 + h;
        dst[(size_t)row * 192 + col] = f2bf((acc[mi][ni][r] + wb[seg * 192 + col]) * sc);
      }
}

// ---------------- attention: full-window, single-buffer, bf16 bias table, setprio ----------------
__global__ __launch_bounds__(256, 3) void attn_kernel(const short* __restrict__ qb,
                                                      const short* __restrict__ kb,
                                                      const short* __restrict__ vb,
                                                      const short* __restrict__ btb,
                                                      short* __restrict__ ao) {
  __shared__ short K_lds[64 * 40];
  __shared__ short Vt_lds[32 * 72];
  __shared__ float l_lds[256];
  const int tid = threadIdx.x;
  const int win = blockIdx.x, head = blockIdx.y;
  const int b = win >> 6, wy = (win >> 3) & 7, wx = win & 7;
  const int w = tid >> 6, lane = tid & 63, c = lane & 31, hi = lane >> 5;

  bh8 qf[2][2];
#pragma unroll
  for (int qi = 0; qi < 2; qi++) {
    int ql = w * 64 + qi * 32 + c;
    size_t gl = (size_t)(b * 16384 + (wy * 16 + (ql >> 4)) * 128 + wx * 16 + (ql & 15));
#pragma unroll
    for (int ds = 0; ds < 2; ds++)
      qf[qi][ds] = *(const bh8*)(qb + gl * 192 + head * 32 + ds * 16 + hi * 8);
  }
  float l_run[2] = {0.f, 0.f};
  fx16 out[2];
#pragma unroll
  for (int r = 0; r < 16; r++) { out[0][r] = 0.f; out[1][r] = 0.f; }

  const int hw9 = (head * 4 + w) * 9;

  const int kl_a = tid >> 2, part_a = tid & 3;
  const int kl_b = tid & 63, hg_b = tid >> 6;

  for (int kc = 0; kc < 9; kc++) {
    __syncthreads();
    {
      int key = kc * 64 + kl_a;
      int ky = key / 24, kx = key - ky * 24;
      int py = wy * 16 - 4 + ky, px = wx * 16 - 4 + kx;
      bh8 kv = {};
      if ((unsigned)py < 128u && (unsigned)px < 128u)
        kv = *(const bh8*)(kb + ((size_t)(b * 16384 + py * 128 + px)) * 192 + head * 32 + part_a * 8);
      *(bh8*)&K_lds[kl_a * 40 + part_a * 8] = kv;

      int key2 = kc * 64 + kl_b;
      int ky2 = key2 / 24, kx2 = key2 - ky2 * 24;
      int py2 = wy * 16 - 4 + ky2, px2 = wx * 16 - 4 + kx2;
      bh8 vv = {};
      if ((unsigned)py2 < 128u && (unsigned)px2 < 128u)
        vv = *(const bh8*)(vb + ((size_t)(b * 16384 + py2 * 128 + px2)) * 192 + head * 32 + hg_b * 8);
#pragma unroll
      for (int j = 0; j < 8; j++) Vt_lds[(hg_b * 8 + j) * 72 + kl_b] = vv[j];
    }
    __syncthreads();

    const short* base_kc = btb + (size_t)(hw9 + kc) * 4096 + lane * 16;
#pragma unroll
    for (int ki = 0; ki < 2; ki++) {
      fx16 st[2];
#pragma unroll
      for (int qi = 0; qi < 2; qi++) {
        const short* bp = base_kc + (ki * 2 + qi) * 1024;
        int4 b0 = *(const int4*)bp;
        int4 b1 = *(const int4*)(bp + 8);
#pragma unroll
        for (int d = 0; d < 4; d++) {
          unsigned u0 = ((const unsigned*)&b0)[d];
          unsigned u1 = ((const unsigned*)&b1)[d];
          st[qi][2 * d]     = __builtin_bit_cast(float, u0 << 16);
          st[qi][2 * d + 1] = __builtin_bit_cast(float, u0 & 0xffff0000u);
          st[qi][8 + 2 * d]     = __builtin_bit_cast(float, u1 << 16);
          st[qi][8 + 2 * d + 1] = __builtin_bit_cast(float, u1 & 0xffff0000u);
        }
      }
      __builtin_amdgcn_s_setprio(1);
#pragma unroll
      for (int ds = 0; ds < 2; ds++) {
        bh8 kf = *(bh8*)&K_lds[(ki * 32 + c) * 40 + ds * 16 + hi * 8];
        st[0] = mfma32(kf, qf[0][ds], st[0]);
        st[1] = mfma32(kf, qf[1][ds], st[1]);
      }
      __builtin_amdgcn_s_setprio(0);
#pragma unroll
      for (int qi = 0; qi < 2; qi++) {
        float s = 0.f;
#pragma unroll
        for (int r = 0; r < 16; r++) {
          float p = fexp2(st[qi][r]);
          st[qi][r] = p;
          s += p;
        }
        l_run[qi] += s;
      }
      int dwq[2][2][4];
#pragma unroll
      for (int qi = 0; qi < 2; qi++)
#pragma unroll
        for (int k1 = 0; k1 < 2; k1++)
#pragma unroll
          for (int p01 = 0; p01 < 2; p01++) {
            int rA = 2 * p01 + 8 * k1;
            int A, Bv;
            asm("v_cvt_pk_bf16_f32 %0, %1, %2" : "=v"(A)  : "v"(st[qi][rA]),     "v"(st[qi][rA + 1]));
            asm("v_cvt_pk_bf16_f32 %0, %1, %2" : "=v"(Bv) : "v"(st[qi][rA + 4]), "v"(st[qi][rA + 5]));
#if __has_builtin(__builtin_amdgcn_permlane32_swap)
            auto pr = __builtin_amdgcn_permlane32_swap((unsigned)A, (unsigned)Bv, false, false);
            dwq[qi][k1][p01]     = (int)pr[0];
            dwq[qi][k1][p01 + 2] = (int)pr[1];
#else
            int Ax = __shfl_xor(A, 32);
            int Bx = __shfl_xor(Bv, 32);
            dwq[qi][k1][p01]     = hi ? Bx : A;
            dwq[qi][k1][p01 + 2] = hi ? Bv : Ax;
#endif
          }
      __builtin_amdgcn_s_setprio(1);
#pragma unroll
      for (int k1 = 0; k1 < 2; k1++) {
        bh8 bv2 = *(bh8*)&Vt_lds[c * 72 + (ki * 2 + k1) * 16 + hi * 8];
#pragma unroll
        for (int qi = 0; qi < 2; qi++) {
          int4 t4 = {dwq[qi][k1][0], dwq[qi][k1][1], dwq[qi][k1][2], dwq[qi][k1][3]};
          out[qi] = mfma32(__builtin_bit_cast(bh8, t4), bv2, out[qi]);
        }
      }
      __builtin_amdgcn_s_setprio(0);
    }
  }
#pragma unroll
  for (int qi = 0; qi < 2; qi++) {
    float lp = l_run[qi] + __shfl_xor(l_run[qi], 32);
    l_lds[w * 64 + qi * 32 + c] = 1.f / lp;
  }
  __syncthreads();
#pragma unroll
  for (int qi = 0; qi < 2; qi++)
#pragma unroll
    for (int r = 0; r < 16; r++) {
      int row = (r & 3) + 8 * (r >> 2) + 4 * hi;
      float val = out[qi][r] * l_lds[w * 64 + qi * 32 + row];
      int ql = w * 64 + qi * 32 + row;
      ao[((size_t)(win * 256 + ql)) * 192 + head * 32 + c] = f2bf(val);
    }
}

// ---------------- proj GEMM: residual 1 -> bf16 x1b + iln2 partials ----------------
__global__ __launch_bounds__(256) void gemm_proj(const short* __restrict__ ao,
                                                 const short* __restrict__ wp,
                                                 const float* __restrict__ wb,
                                                 const float* __restrict__ x,
                                                 const float* __restrict__ ls1,
                                                 const float* __restrict__ st,
                                                 short* __restrict__ x1b,
                                                 float* __restrict__ part2) {
  __shared__ float red[512];
  const int m0 = blockIdx.x * 128, by = blockIdx.y;
  const int tid = threadIdx.x, wid = tid >> 6, lane = tid & 63;
  const int g = lane >> 4, h = lane & 15;
  const int wm = wid >> 1, wn = wid & 1;
  fx4 acc[4][3];
#pragma unroll
  for (int i = 0; i < 4; i++)
#pragma unroll
    for (int j = 0; j < 3; j++) acc[i][j] = fzero();

#pragma unroll
  for (int kt = 0; kt < 6; kt++) {
    bh8 af[4], bf[3];
#pragma unroll
    for (int mi = 0; mi < 4; mi++)
      af[mi] = *(const bh8*)(ao + (size_t)(m0 + wm * 64 + mi * 16 + h) * 192 + kt * 32 + g * 8);
#pragma unroll
    for (int ni = 0; ni < 3; ni++)
      bf[ni] = *(const bh8*)(wp + (size_t)(((by * 6 + kt) * 2 + wn) * 3 + ni) * 512 + lane * 8);
#pragma unroll
    for (int ni = 0; ni < 3; ni++)
#pragma unroll
      for (int mi = 0; mi < 4; mi++) acc[mi][ni] = mfma16(af[mi], bf[ni], acc[mi][ni]);
  }
  const int n0 = by * 96;
  float ps = 0.f, ps2 = 0.f;
#pragma unroll
  for (int mi = 0; mi < 4; mi++)
#pragma unroll
    for (int ni = 0; ni < 3; ni++)
#pragma unroll
      for (int r = 0; r < 4; r++) {
        int grow = m0 + wm * 64 + mi * 16 + g * 4 + r;
        int win = grow >> 8, q = grow & 255;
        int bb = win >> 6, wy = (win >> 3) & 7, wxx = win & 7;
        int l = (wy * 16 + (q >> 4)) * 128 + wxx * 16 + (q & 15);
        int col = n0 + wn * 48 + ni * 16 + h;
        size_t di = ((size_t)(bb * 16384 + l)) * 192 + col;
        float s1 = st[bb * 2 + 1];
        float val = x[di] + s1 * ls1[col] * (acc[mi][ni][r] + wb[col]);
        x1b[di] = f2bf(val);
        ps += val;
        ps2 += val * val;
      }
  red[tid] = ps; red[256 + tid] = ps2;
  __syncthreads();
  for (int s = 128; s > 0; s >>= 1) {
    if (tid < s) { red[tid] += red[tid + s]; red[256 + tid] += red[256 + tid + s]; }
    __syncthreads();
  }
  if (tid == 0) {
    int pi = blockIdx.x * 2 + by;
    part2[pi * 2] = red[0];
    part2[pi * 2 + 1] = red[256];
  }
}

// ---------------- fcgv GEMM: barrier-free fragment loop + SiLU -> planar hp ----------------
__global__ __launch_bounds__(256) void gemm_fcgv(const short* __restrict__ x1n,
                                                 const short* __restrict__ wg,
                                                 const float* __restrict__ wb,
                                                 short* __restrict__ hp) {
  __shared__ short T[64 * 136];
  const int mt = blockIdx.x, by = blockIdx.y, n0 = by * 64;
  const int m0 = mt * 128;
  const int b = m0 >> 14, l0 = m0 & 16383;
  const int tid = threadIdx.x, wid = tid >> 6, lane = tid & 63;
  const int g = lane >> 4, h = lane & 15;
  const int wm = wid >> 1, wn = wid & 1;
  fx4 accg[4][2], accv[4][2];
#pragma unroll
  for (int i = 0; i < 4; i++)
#pragma unroll
    for (int j = 0; j < 2; j++) { accg[i][j] = fzero(); accv[i][j] = fzero(); }

#pragma unroll
  for (int kt = 0; kt < 6; kt++) {
    bh8 af[4], bg[2], bv[2];
#pragma unroll
    for (int mi = 0; mi < 4; mi++)
      af[mi] = *(const bh8*)(x1n + (size_t)((((mt * 2 + wm) * 4 + mi) * 6 + kt)) * 512 + lane * 8);
#pragma unroll
    for (int ni = 0; ni < 2; ni++) {
      size_t base = (size_t)((((by * 6 + kt) * 2 + wn) * 2 + ni) * 2) * 512;
      bg[ni] = *(const bh8*)(wg + base + lane * 8);
      bv[ni] = *(const bh8*)(wg + base + 512 + lane * 8);
    }
#pragma unroll
    for (int ni = 0; ni < 2; ni++)
#pragma unroll
      for (int mi = 0; mi < 4; mi++) {
        accg[mi][ni] = mfma16(af[mi], bg[ni], accg[mi][ni]);
        accv[mi][ni] = mfma16(af[mi], bv[ni], accv[mi][ni]);
      }
  }
  short hs[4][2][4];
#pragma unroll
  for (int mi = 0; mi < 4; mi++)
#pragma unroll
    for (int ni = 0; ni < 2; ni++)
#pragma unroll
      for (int r = 0; r < 4; r++) {
        int colg = n0 + wn * 32 + ni * 16 + h;
        float gv = accg[mi][ni][r] + wb[colg];
        float vv = accv[mi][ni][r] + wb[512 + colg];
        hs[mi][ni][r] = f2bf(gv / (1.f + __expf(-gv)) * vv);
      }
#pragma unroll
  for (int mi = 0; mi < 4; mi++)
#pragma unroll
    for (int ni = 0; ni < 2; ni++)
#pragma unroll
      for (int r = 0; r < 4; r++) {
        int cc = wn * 32 + ni * 16 + h;
        int rl = wm * 64 + mi * 16 + g * 4 + r;
        T[cc * 136 + rl] = hs[mi][ni][r];
      }
  __syncthreads();
#pragma unroll
  for (int i = 0; i < 4; i++) {
    int ch = tid + i * 256;
    int cc = ch >> 4, lg = ch & 15;
    bh8 v = *(bh8*)&T[cc * 136 + lg * 8];
    *(bh8*)(hp + (((size_t)(b * 512 + n0 + cc)) << 14) + l0 + lg * 8) = v;
  }
}

// ---------------- fused depthwise convs: 64-row stripes, out-of-place ----------------
__global__ __launch_bounds__(256) void dw_fused(const short* __restrict__ in,
                                                const float* __restrict__ w1,
                                                const float* __restrict__ b1,
                                                const float* __restrict__ w2,
                                                const float* __restrict__ b2,
                                                const float* __restrict__ dsc,
                                                short* __restrict__ outp) {
  __shared__ short P[70 * 136];
  __shared__ short D[68 * 136];
  const int p = blockIdx.x >> 1, s = blockIdx.x & 1, c = p & 511;
  const int tid = threadIdx.x;
  const int r0 = s * 64;
  const int plo = s ? 61 : 0;
  const int pbase = r0 - 3;
  const int dlo = s ? 62 : 0;
  const int dbase = r0 - 2;
  const short* ip = in + ((size_t)p << 14);

  for (int i = tid; i < 67 * 16; i += 256) {
    int rr = plo + (i >> 4), sl = i & 15;
    bh8 v = *(const bh8*)(ip + rr * 128 + sl * 8);
    *(bh8*)&P[(rr - pbase) * 136 + sl * 8] = v;
  }
  float k1[9], k2[9];
#pragma unroll
  for (int j = 0; j < 9; j++) { k1[j] = w1[c * 9 + j]; k2[j] = w2[c * 9 + j]; }
  const float bias1 = b1[c], bias2 = b2[c], ds = dsc[0];
  __syncthreads();

  for (int i = tid; i < 66 * 16; i += 256) {
    int gy = dlo + (i >> 4);
    int x0 = (i & 15) * 8;
    float acc[8];
#pragma unroll
    for (int q = 0; q < 8; q++) acc[q] = bias1;
#pragma unroll
    for (int ky = 0; ky < 3; ky++) {
      int yy = gy + ky - 1;
      if ((unsigned)yy < 128u) {
        const short* row = &P[(yy - pbase) * 136];
        float f[10];
        bh8 v = *(const bh8*)&row[x0];
#pragma unroll
        for (int j = 0; j < 8; j++) f[j + 1] = bf2f(v[j]);
        f[0] = (x0 == 0) ? 0.f : bf2f(row[x0 - 1]);
        f[9] = (x0 == 120) ? 0.f : bf2f(row[x0 + 8]);
        float w0 = k1[ky * 3], wA = k1[ky * 3 + 1], wB = k1[ky * 3 + 2];
#pragma unroll
        for (int q = 0; q < 8; q++) acc[q] += f[q] * w0 + f[q + 1] * wA + f[q + 2] * wB;
      }
    }
    bh8 pk;
#pragma unroll
    for (int q = 0; q < 8; q++) pk[q] = f2bf(acc[q]);
    *(bh8*)&D[(gy - dbase) * 136 + x0] = pk;
  }
  __syncthreads();

  for (int i = tid; i < 64 * 16; i += 256) {
    int gy = r0 + (i >> 4);
    int x0 = (i & 15) * 8;
    float acc[8], center[8];
#pragma unroll
    for (int q = 0; q < 8; q++) acc[q] = bias2;
#pragma unroll
    for (int ky = 0; ky < 3; ky++) {
      int yy = gy + (ky - 1) * 2;
      if ((unsigned)yy < 128u) {
        const short* row = &D[(yy - dbase) * 136];
        float f[12];
        bh8 v = *(const bh8*)&row[x0];
#pragma unroll
        for (int j = 0; j < 8; j++) f[j + 2] = bf2f(v[j]);
        if (x0 == 0) { f[0] = 0.f; f[1] = 0.f; }
        else {
          unsigned lp = *(const unsigned*)&row[x0 - 2];
          f[0] = __builtin_bit_cast(float, lp << 16);
          f[1] = __builtin_bit_cast(float, lp & 0xffff0000u);
        }
        if (x0 == 120) { f[10] = 0.f; f[11] = 0.f; }
        else {
          unsigned rp = *(const unsigned*)&row[x0 + 8];
          f[10] = __builtin_bit_cast(float, rp << 16);
          f[11] = __builtin_bit_cast(float, rp & 0xffff0000u);
        }
        float w0 = k2[ky * 3], wA = k2[ky * 3 + 1], wB = k2[ky * 3 + 2];
#pragma unroll
        for (int q = 0; q < 8; q++) acc[q] += f[q] * w0 + f[q + 2] * wA + f[q + 4] * wB;
        if (ky == 1) {
#pragma unroll
          for (int q = 0; q < 8; q++) center[q] = f[q + 2];
        }
      }
    }
    bh8 pk;
#pragma unroll
    for (int q = 0; q < 8; q++) pk[q] = f2bf(center[q] + ds * acc[q]);
    *(bh8*)(outp + ((size_t)p << 14) + gy * 128 + x0) = pk;
  }
}

// ---------------- fco GEMM: A via LDS transpose, B fragments, bf16 residual ----------------
__global__ __launch_bounds__(256) void gemm_fco(const short* __restrict__ h2,
                                                const short* __restrict__ wo,
                                                const float* __restrict__ wb,
                                                const short* __restrict__ x1b,
                                                const float* __restrict__ ls2,
                                                const float* __restrict__ st,
                                                float* __restrict__ out) {
  __shared__ short As[128 * 40];
  const int m0 = blockIdx.x * 128, by = blockIdx.y, n0 = by * 96;
  const int b = m0 >> 14, l0 = m0 & 16383;
  const int tid = threadIdx.x, wid = tid >> 6, lane = tid & 63;
  const int g = lane >> 4, h = lane & 15;
  const int wm = wid >> 1, wn = wid & 1;
  const int cp = tid & 15, lg = tid >> 4;
  fx4 acc[4][3];
#pragma unroll
  for (int i = 0; i < 4; i++)
#pragma unroll
    for (int j = 0; j < 3; j++) acc[i][j] = fzero();

  for (int kt = 0; kt < 16; kt++) {
    const int k0 = kt * 32;
    {
      const short* basep = h2 + (((size_t)(b * 512 + k0 + 2 * cp)) << 14) + l0 + lg * 8;
      bh8 v0 = *(const bh8*)basep;
      bh8 v1 = *(const bh8*)(basep + 16384);
#pragma unroll
      for (int j = 0; j < 8; j++) {
        unsigned pkv = (unsigned)(unsigned short)v0[j] | (((unsigned)(unsigned short)v1[j]) << 16);
        *(unsigned*)&As[(lg * 8 + j) * 40 + 2 * cp] = pkv;
      }
    }
    __syncthreads();
    bh8 af[4], bf[3];
#pragma unroll
    for (int mi = 0; mi < 4; mi++)
      af[mi] = *(bh8*)&As[(wm * 64 + mi * 16 + h) * 40 + g * 8];
#pragma unroll
    for (int ni = 0; ni < 3; ni++)
      bf[ni] = *(const bh8*)(wo + (size_t)(((by * 16 + kt) * 2 + wn) * 3 + ni) * 512 + lane * 8);
#pragma unroll
    for (int ni = 0; ni < 3; ni++)
#pragma unroll
      for (int mi = 0; mi < 4; mi++) acc[mi][ni] = mfma16(af[mi], bf[ni], acc[mi][ni]);
    __syncthreads();
  }
  float s2 = st[b * 2 + 1];
#pragma unroll
  for (int mi = 0; mi < 4; mi++)
#pragma unroll
    for (int ni = 0; ni < 3; ni++)
#pragma unroll
      for (int r = 0; r < 4; r++) {
        int row = m0 + wm * 64 + mi * 16 + g * 4 + r;
        int col = n0 + wn * 48 + ni * 16 + h;
        size_t di = (size_t)row * 192 + col;
        out[di] = bf2f(x1b[di]) + s2 * ls2[col] * (acc[mi][ni][r] + wb[col]);
      }
}

extern "C" void kernel_launch(void* const* d_in, const int* in_sizes, int n_in,
                              void* d_out, int out_size, void* d_ws, size_t ws_size,
                              hipStream_t stream) {
  const float* x      = (const float*)d_in[0];
  const float* qkv_w  = (const float*)d_in[1];
  const float* qkv_b  = (const float*)d_in[2];
  const float* proj_w = (const float*)d_in[3];
  const float* proj_b = (const float*)d_in[4];
  const float* rpb    = (const float*)d_in[5];
  const float* n1_w   = (const float*)d_in[6];
  const float* n1_b   = (const float*)d_in[7];
  const float* ls1    = (const float*)d_in[8];
  const float* n2_w   = (const float*)d_in[9];
  const float* n2_b   = (const float*)d_in[10];
  const float* ls2    = (const float*)d_in[11];
  const float* fcgv_w = (const float*)d_in[12];
  const float* fcgv_b = (const float*)d_in[13];
  const float* dw_w   = (const float*)d_in[14];
  const float* dw_b   = (const float*)d_in[15];
  const float* dwd_w  = (const float*)d_in[16];
  const float* dwd_b  = (const float*)d_in[17];
  const float* dil    = (const float*)d_in[18];
  const float* fco_w  = (const float*)d_in[19];
  const float* fco_b  = (const float*)d_in[20];
  float* out = (float*)d_out;
  char* ws = (char*)d_ws;

  // workspace layout (bytes); peak ~104.5 MB
  short* wbuf = (short*)(ws + 0);
  short* wq = wbuf;
  short* wp = wbuf + 110592;
  short* wg = wbuf + 147456;
  short* wo = wbuf + 344064;
  float* part  = (float*)(ws + 884736);
  float* st1   = (float*)(ws + 891904);
  float* st2   = (float*)(ws + 891968);
  float* part2 = (float*)(ws + 892032);
  short* xn  = (short*)(ws + 1048576);       // 12.58 MB (dead after qkv)
  short* btb = (short*)(ws + 13631488);      // 1.77 MB (dead after attn)
  short* qb  = (short*)(ws + 17301504);      // 12.58 MB (dead after attn)
  short* kb  = (short*)(ws + 29884416);      // 12.58 MB (dead after attn)
  short* vb  = (short*)(ws + 42467328);      // 12.58 MB (dead after attn)
  short* ao  = (short*)(ws + 55050240);      // 12.58 MB (dead after proj)
  short* x1b = (short*)(ws + 1048576);       // 12.58 MB bf16 (over xn, dead after qkv)
  short* x1n = (short*)(ws + 26214400);      // 12.58 MB fragment order (over qb-tail/kb-head)
  short* hp  = (short*)(ws + 42467328);      // 33.55 MB (over vb+ao)
  short* h2  = (short*)(ws + 76021760);      // 33.55 MB dw output

  iln_partial<<<512, 256, 0, stream>>>(x, part);
  prep<<<432, 256, 0, stream>>>(qkv_w, proj_w, fcgv_w, fco_w, rpb, wbuf, btb);
  cvt_aff<<<3072, 256, 0, stream>>>(x, part, n1_w, n1_b, xn, st1);
  gemm_qkv<<<dim3(256, 6), 256, 0, stream>>>(xn, wq, qkv_b, qb, kb, vb);
  attn_kernel<<<dim3(128, 6), 256, 0, stream>>>(qb, kb, vb, btb, ao);
  gemm_proj<<<dim3(256, 2), 256, 0, stream>>>(ao, wp, proj_b, x, ls1, st1, x1b, part2);
  cvt_affb<<<3072, 256, 0, stream>>>(x1b, part2, n2_w, n2_b, x1n, st2);
  gemm_fcgv<<<dim3(256, 8), 256, 0, stream>>>(x1n, wg, fcgv_b, hp);
  dw_fused<<<2048, 256, 0, stream>>>(hp, dw_w, dw_b, dwd_w, dwd_b, dil, h2);
  gemm_fco<<<dim3(256, 2), 256, 0, stream>>>(h2, wo, fco_b, x1b, ls2, st2, out);
}

// Round 17
// 169.297 us; speedup vs baseline: 1.0858x; 1.0029x over previous
//
#include <hip/hip_runtime.h>

#define DI __device__ __forceinline__

typedef __attribute__((ext_vector_type(8))) short bh8;
typedef __attribute__((ext_vector_type(4))) float fx4;
typedef __attribute__((ext_vector_type(16))) float fx16;

DI short f2bf(float f) {
  unsigned u = __builtin_bit_cast(unsigned, f);
  u += 0x7FFFu + ((u >> 16) & 1u);
  return (short)(u >> 16);
}
DI float bf2f(short s) {
  unsigned u = ((unsigned)(unsigned short)s) << 16;
  return __builtin_bit_cast(float, u);
}
DI fx4 mfma16(bh8 a, bh8 b, fx4 c) {
  return __builtin_amdgcn_mfma_f32_16x16x32_bf16(a, b, c, 0, 0, 0);
}
DI fx16 mfma32(bh8 a, bh8 b, fx16 c) {
  return __builtin_amdgcn_mfma_f32_32x32x16_bf16(a, b, c, 0, 0, 0);
}
DI fx4 fzero() { fx4 z = {0.f, 0.f, 0.f, 0.f}; return z; }

DI float fexp2(float x) {
#if __has_builtin(__builtin_amdgcn_exp2f)
  return __builtin_amdgcn_exp2f(x);
#else
  return exp2f(x);
#endif
}

DI bh8 pack8(const float* src) {
  fx4 v0 = *(const fx4*)src;
  fx4 v1 = *(const fx4*)(src + 4);
  bh8 pk;
#pragma unroll
  for (int j = 0; j < 4; j++) { pk[j] = f2bf(v0[j]); pk[j + 4] = f2bf(v1[j]); }
  return pk;
}

// ---------------- holistic LN stats over x + bf16 copy of x ----------------
__global__ __launch_bounds__(256) void iln_partial(const float* __restrict__ x,
                                                   float* __restrict__ part,
                                                   short* __restrict__ xb) {
  const int blk = blockIdx.x, tid = threadIdx.x;
  const fx4* p = (const fx4*)(x + (size_t)blk * 12288);
  short* xbp = xb + (size_t)blk * 12288;
  float s = 0.f, s2 = 0.f;
#pragma unroll
  for (int i = 0; i < 12; i++) {
    fx4 v = p[i * 256 + tid];
    s  += v[0] + v[1] + v[2] + v[3];
    s2 += v[0] * v[0] + v[1] * v[1] + v[2] * v[2] + v[3] * v[3];
    short o4[4];
#pragma unroll
    for (int j = 0; j < 4; j++) o4[j] = f2bf(v[j]);
    *(unsigned long long*)(xbp + (i * 256 + tid) * 4) = *(unsigned long long*)o4;
  }
  __shared__ float sm[512];
  sm[tid] = s; sm[256 + tid] = s2;
  __syncthreads();
  for (int st = 128; st > 0; st >>= 1) {
    if (tid < st) { sm[tid] += sm[tid + st]; sm[256 + tid] += sm[256 + tid + st]; }
    __syncthreads();
  }
  if (tid == 0) { part[blk * 2] = sm[0]; part[blk * 2 + 1] = sm[256]; }
}

// ---------------- prep: weight convert (fragment layout) + bf16 bias table ----------------
__global__ __launch_bounds__(256) void prep(const float* __restrict__ qkv_w,
                                            const float* __restrict__ proj_w,
                                            const float* __restrict__ fcgv_w,
                                            const float* __restrict__ fco_w,
                                            const float* __restrict__ rpb,
                                            short* __restrict__ wbuf,
                                            short* __restrict__ btb) {
  if (blockIdx.x < 216) {
    int t = blockIdx.x * 256 + threadIdx.x;
    int blk = t >> 6, lane = t & 63;
    int g = lane >> 4, h = lane & 15;
    const float* src;
    if (blk < 216) {
      int b2 = blk;
      int ni = b2 % 3; b2 /= 3;
      int wn = b2 & 1; b2 >>= 1;
      int kt = b2 % 6; b2 /= 6;
      int nt = b2;
      src = qkv_w + (size_t)(nt * 96 + wn * 48 + ni * 16 + h) * 192 + kt * 32 + g * 8;
    } else if (blk < 288) {
      int b2 = blk - 216;
      int ni = b2 % 3; b2 /= 3;
      int wn = b2 & 1; b2 >>= 1;
      int kt = b2 % 6; b2 /= 6;
      int nt = b2;
      src = proj_w + (size_t)(nt * 96 + wn * 48 + ni * 16 + h) * 192 + kt * 32 + g * 8;
    } else if (blk < 672) {
      int b2 = blk - 288;
      int gv = b2 & 1; b2 >>= 1;
      int ni = b2 & 1; b2 >>= 1;
      int wn = b2 & 1; b2 >>= 1;
      int kt = b2 % 6; b2 /= 6;
      int nt = b2;
      int r = wn * 32 + ni * 16 + h;
      int row = gv ? (512 + nt * 64 + r) : (nt * 64 + r);
      src = fcgv_w + (size_t)row * 192 + kt * 32 + g * 8;
    } else {
      int b2 = blk - 672;
      int ni = b2 % 3; b2 /= 3;
      int wn = b2 & 1; b2 >>= 1;
      int kt = b2 & 15; b2 >>= 4;
      int nt = b2;
      src = fco_w + (size_t)(nt * 96 + wn * 48 + ni * 16 + h) * 512 + kt * 32 + g * 8;
    }
    *(bh8*)(wbuf + (size_t)blk * 512 + lane * 8) = pack8(src);
  } else {
    int t = (blockIdx.x - 216) * 256 + threadIdx.x;  // 55296
    int lane = t & 63;
    int u = t >> 6;
    int qi = u & 1;
    int c = lane & 31, hi = lane >> 5;
    int w = (u >> 2) / 9 % 4;
    int head = (u >> 2) / 36;
    int q = w * 64 + qi * 32 + c;
    int qterm = (q >> 4) * 39 + (q & 15);
    short o16[16];
#pragma unroll
    for (int r = 0; r < 16; r++) {
      int kk = ((u >> 2) % 9) * 64 + ((u >> 1) & 1) * 32 + (r & 3) + 8 * (r >> 2) + 4 * hi;
      int ky = (kk * 2731) >> 16;
      int kx = kk - ky * 24;
      int idx = ky * 39 + kx + 600 - qterm;
      o16[r] = f2bf(rpb[idx * 6 + head] * 1.4426950408889634f);
    }
    *(bh8*)(btb + (size_t)u * 1024 + lane * 16)     = *(bh8*)&o16[0];
    *(bh8*)(btb + (size_t)u * 1024 + lane * 16 + 8) = *(bh8*)&o16[8];
  }
}

// ---------------- activation convert (bf16 src) -> A-fragment layout, fused iln-final ----------------
__global__ __launch_bounds__(256) void cvt_affb(const short* __restrict__ src,
                                                const float* __restrict__ part,
                                                const float* __restrict__ w,
                                                const float* __restrict__ bias,
                                                short* __restrict__ dst,
                                                float* __restrict__ st) {
  __shared__ float rs[512];
  const int tid = threadIdx.x;
  const int bb = (blockIdx.x >= 1536) ? 1 : 0;
  rs[tid]       = part[(bb * 256 + tid) * 2];
  rs[256 + tid] = part[(bb * 256 + tid) * 2 + 1];
  __syncthreads();
  for (int s = 128; s > 0; s >>= 1) {
    if (tid < s) { rs[tid] += rs[tid + s]; rs[256 + tid] += rs[256 + tid + s]; }
    __syncthreads();
  }
  const float invn = 1.f / 3145728.f;
  float mean = rs[0] * invn;
  float var  = rs[256] * invn - mean * mean;
  float scale = fminf(sqrtf(var + 1e-6f), 2.f);
  if (tid == 0 && (blockIdx.x == 0 || blockIdx.x == 1536)) {
    st[bb * 2] = mean;
    st[bb * 2 + 1] = scale;
  }
  const float isc = 1.f / scale;
  int t = blockIdx.x * 256 + tid;
  int row = t / 24;
  int c0 = (t - row * 24) * 8;
  int mt = row >> 7, wm = (row >> 6) & 1, mi = (row >> 4) & 3, h = row & 15;
  int kt = c0 >> 5, g = (c0 >> 3) & 3;
  int blk = ((mt * 2 + wm) * 4 + mi) * 6 + kt;
  int lane = g * 16 + h;
  bh8 v = *(const bh8*)(src + (size_t)row * 192 + c0);
  bh8 pk;
#pragma unroll
  for (int j = 0; j < 8; j++) {
    float a = w[c0 + j] * isc;
    pk[j] = f2bf(bf2f(v[j]) * a + (bias[c0 + j] - mean * a));
  }
  *(bh8*)(dst + (size_t)blk * 512 + lane * 8) = pk;
}

// ---------------- QKV GEMM: barrier-free, fragment operands ----------------
__global__ __launch_bounds__(256) void gemm_qkv(const short* __restrict__ xn,
                                                const short* __restrict__ wq,
                                                const float* __restrict__ wb,
                                                short* __restrict__ qb,
                                                short* __restrict__ kb,
                                                short* __restrict__ vb) {
  const int mt = blockIdx.x, by = blockIdx.y;
  const int m0 = mt * 128;
  const int tid = threadIdx.x, wid = tid >> 6, lane = tid & 63;
  const int g = lane >> 4, h = lane & 15;
  const int wm = wid >> 1, wn = wid & 1;
  fx4 acc[4][3];
#pragma unroll
  for (int i = 0; i < 4; i++)
#pragma unroll
    for (int j = 0; j < 3; j++) acc[i][j] = fzero();

#pragma unroll
  for (int kt = 0; kt < 6; kt++) {
    bh8 af[4], bf[3];
#pragma unroll
    for (int mi = 0; mi < 4; mi++)
      af[mi] = *(const bh8*)(xn + (size_t)((((mt * 2 + wm) * 4 + mi) * 6 + kt)) * 512 + lane * 8);
#pragma unroll
    for (int ni = 0; ni < 3; ni++)
      bf[ni] = *(const bh8*)(wq + (size_t)(((by * 6 + kt) * 2 + wn) * 3 + ni) * 512 + lane * 8);
#pragma unroll
    for (int ni = 0; ni < 3; ni++)
#pragma unroll
      for (int mi = 0; mi < 4; mi++) acc[mi][ni] = mfma16(af[mi], bf[ni], acc[mi][ni]);
  }
  const int seg = by >> 1;
  short* dst = (seg == 0) ? qb : (seg == 1 ? kb : vb);
  const float sc = (seg == 1) ? 0.25503486f : 1.0f;  // SCALE * log2(e) folded into K
  const int colbase = (by & 1) * 96;
#pragma unroll
  for (int mi = 0; mi < 4; mi++)
#pragma unroll
    for (int ni = 0; ni < 3; ni++)
#pragma unroll
      for (int r = 0; r < 4; r++) {
        int row = m0 + wm * 64 + mi * 16 + g * 4 + r;
        int col = colbase + wn * 48 + ni * 16 + h;
        dst[(size_t)row * 192 + col] = f2bf((acc[mi][ni][r] + wb[seg * 192 + col]) * sc);
      }
}

// ---------------- attention: full-window, single-buffer, bf16 bias table, setprio ----------------
__global__ __launch_bounds__(256, 3) void attn_kernel(const short* __restrict__ qb,
                                                      const short* __restrict__ kb,
                                                      const short* __restrict__ vb,
                                                      const short* __restrict__ btb,
                                                      short* __restrict__ ao) {
  __shared__ short K_lds[64 * 40];
  __shared__ short Vt_lds[32 * 72];
  __shared__ float l_lds[256];
  const int tid = threadIdx.x;
  const int win = blockIdx.x, head = blockIdx.y;
  const int b = win >> 6, wy = (win >> 3) & 7, wx = win & 7;
  const int w = tid >> 6, lane = tid & 63, c = lane & 31, hi = lane >> 5;

  bh8 qf[2][2];
#pragma unroll
  for (int qi = 0; qi < 2; qi++) {
    int ql = w * 64 + qi * 32 + c;
    size_t gl = (size_t)(b * 16384 + (wy * 16 + (ql >> 4)) * 128 + wx * 16 + (ql & 15));
#pragma unroll
    for (int ds = 0; ds < 2; ds++)
      qf[qi][ds] = *(const bh8*)(qb + gl * 192 + head * 32 + ds * 16 + hi * 8);
  }
  float l_run[2] = {0.f, 0.f};
  fx16 out[2];
#pragma unroll
  for (int r = 0; r < 16; r++) { out[0][r] = 0.f; out[1][r] = 0.f; }

  const int hw9 = (head * 4 + w) * 9;

  const int kl_a = tid >> 2, part_a = tid & 3;
  const int kl_b = tid & 63, hg_b = tid >> 6;

  for (int kc = 0; kc < 9; kc++) {
    __syncthreads();
    {
      int key = kc * 64 + kl_a;
      int ky = key / 24, kx = key - ky * 24;
      int py = wy * 16 - 4 + ky, px = wx * 16 - 4 + kx;
      bh8 kv = {};
      if ((unsigned)py < 128u && (unsigned)px < 128u)
        kv = *(const bh8*)(kb + ((size_t)(b * 16384 + py * 128 + px)) * 192 + head * 32 + part_a * 8);
      *(bh8*)&K_lds[kl_a * 40 + part_a * 8] = kv;

      int key2 = kc * 64 + kl_b;
      int ky2 = key2 / 24, kx2 = key2 - ky2 * 24;
      int py2 = wy * 16 - 4 + ky2, px2 = wx * 16 - 4 + kx2;
      bh8 vv = {};
      if ((unsigned)py2 < 128u && (unsigned)px2 < 128u)
        vv = *(const bh8*)(vb + ((size_t)(b * 16384 + py2 * 128 + px2)) * 192 + head * 32 + hg_b * 8);
#pragma unroll
      for (int j = 0; j < 8; j++) Vt_lds[(hg_b * 8 + j) * 72 + kl_b] = vv[j];
    }
    __syncthreads();

    const short* base_kc = btb + (size_t)(hw9 + kc) * 4096 + lane * 16;
#pragma unroll
    for (int ki = 0; ki < 2; ki++) {
      fx16 st[2];
#pragma unroll
      for (int qi = 0; qi < 2; qi++) {
        const short* bp = base_kc + (ki * 2 + qi) * 1024;
        int4 b0 = *(const int4*)bp;
        int4 b1 = *(const int4*)(bp + 8);
#pragma unroll
        for (int d = 0; d < 4; d++) {
          unsigned u0 = ((const unsigned*)&b0)[d];
          unsigned u1 = ((const unsigned*)&b1)[d];
          st[qi][2 * d]     = __builtin_bit_cast(float, u0 << 16);
          st[qi][2 * d + 1] = __builtin_bit_cast(float, u0 & 0xffff0000u);
          st[qi][8 + 2 * d]     = __builtin_bit_cast(float, u1 << 16);
          st[qi][8 + 2 * d + 1] = __builtin_bit_cast(float, u1 & 0xffff0000u);
        }
      }
      __builtin_amdgcn_s_setprio(1);
#pragma unroll
      for (int ds = 0; ds < 2; ds++) {
        bh8 kf = *(bh8*)&K_lds[(ki * 32 + c) * 40 + ds * 16 + hi * 8];
        st[0] = mfma32(kf, qf[0][ds], st[0]);
        st[1] = mfma32(kf, qf[1][ds], st[1]);
      }
      __builtin_amdgcn_s_setprio(0);
#pragma unroll
      for (int qi = 0; qi < 2; qi++) {
        float s = 0.f;
#pragma unroll
        for (int r = 0; r < 16; r++) {
          float p = fexp2(st[qi][r]);
          st[qi][r] = p;
          s += p;
        }
        l_run[qi] += s;
      }
      int dwq[2][2][4];
#pragma unroll
      for (int qi = 0; qi < 2; qi++)
#pragma unroll
        for (int k1 = 0; k1 < 2; k1++)
#pragma unroll
          for (int p01 = 0; p01 < 2; p01++) {
            int rA = 2 * p01 + 8 * k1;
            int A, Bv;
            asm("v_cvt_pk_bf16_f32 %0, %1, %2" : "=v"(A)  : "v"(st[qi][rA]),     "v"(st[qi][rA + 1]));
            asm("v_cvt_pk_bf16_f32 %0, %1, %2" : "=v"(Bv) : "v"(st[qi][rA + 4]), "v"(st[qi][rA + 5]));
#if __has_builtin(__builtin_amdgcn_permlane32_swap)
            auto pr = __builtin_amdgcn_permlane32_swap((unsigned)A, (unsigned)Bv, false, false);
            dwq[qi][k1][p01]     = (int)pr[0];
            dwq[qi][k1][p01 + 2] = (int)pr[1];
#else
            int Ax = __shfl_xor(A, 32);
            int Bx = __shfl_xor(Bv, 32);
            dwq[qi][k1][p01]     = hi ? Bx : A;
            dwq[qi][k1][p01 + 2] = hi ? Bv : Ax;
#endif
          }
      __builtin_amdgcn_s_setprio(1);
#pragma unroll
      for (int k1 = 0; k1 < 2; k1++) {
        bh8 bv2 = *(bh8*)&Vt_lds[c * 72 + (ki * 2 + k1) * 16 + hi * 8];
#pragma unroll
        for (int qi = 0; qi < 2; qi++) {
          int4 t4 = {dwq[qi][k1][0], dwq[qi][k1][1], dwq[qi][k1][2], dwq[qi][k1][3]};
          out[qi] = mfma32(__builtin_bit_cast(bh8, t4), bv2, out[qi]);
        }
      }
      __builtin_amdgcn_s_setprio(0);
    }
  }
#pragma unroll
  for (int qi = 0; qi < 2; qi++) {
    float lp = l_run[qi] + __shfl_xor(l_run[qi], 32);
    l_lds[w * 64 + qi * 32 + c] = 1.f / lp;
  }
  __syncthreads();
#pragma unroll
  for (int qi = 0; qi < 2; qi++)
#pragma unroll
    for (int r = 0; r < 16; r++) {
      int row = (r & 3) + 8 * (r >> 2) + 4 * hi;
      float val = out[qi][r] * l_lds[w * 64 + qi * 32 + row];
      int ql = w * 64 + qi * 32 + row;
      ao[((size_t)(win * 256 + ql)) * 192 + head * 32 + c] = f2bf(val);
    }
}

// ---------------- proj GEMM: residual 1 (bf16 x) -> bf16 x1b + iln2 partials ----------------
__global__ __launch_bounds__(256) void gemm_proj(const short* __restrict__ ao,
                                                 const short* __restrict__ wp,
                                                 const float* __restrict__ wb,
                                                 const short* __restrict__ xb,
                                                 const float* __restrict__ ls1,
                                                 const float* __restrict__ st,
                                                 short* __restrict__ x1b,
                                                 float* __restrict__ part2) {
  __shared__ float red[512];
  const int m0 = blockIdx.x * 128, by = blockIdx.y;
  const int tid = threadIdx.x, wid = tid >> 6, lane = tid & 63;
  const int g = lane >> 4, h = lane & 15;
  const int wm = wid >> 1, wn = wid & 1;
  fx4 acc[4][3];
#pragma unroll
  for (int i = 0; i < 4; i++)
#pragma unroll
    for (int j = 0; j < 3; j++) acc[i][j] = fzero();

#pragma unroll
  for (int kt = 0; kt < 6; kt++) {
    bh8 af[4], bf[3];
#pragma unroll
    for (int mi = 0; mi < 4; mi++)
      af[mi] = *(const bh8*)(ao + (size_t)(m0 + wm * 64 + mi * 16 + h) * 192 + kt * 32 + g * 8);
#pragma unroll
    for (int ni = 0; ni < 3; ni++)
      bf[ni] = *(const bh8*)(wp + (size_t)(((by * 6 + kt) * 2 + wn) * 3 + ni) * 512 + lane * 8);
#pragma unroll
    for (int ni = 0; ni < 3; ni++)
#pragma unroll
      for (int mi = 0; mi < 4; mi++) acc[mi][ni] = mfma16(af[mi], bf[ni], acc[mi][ni]);
  }
  const int n0 = by * 96;
  float ps = 0.f, ps2 = 0.f;
#pragma unroll
  for (int mi = 0; mi < 4; mi++)
#pragma unroll
    for (int ni = 0; ni < 3; ni++)
#pragma unroll
      for (int r = 0; r < 4; r++) {
        int grow = m0 + wm * 64 + mi * 16 + g * 4 + r;
        int win = grow >> 8, q = grow & 255;
        int bb = win >> 6, wy = (win >> 3) & 7, wxx = win & 7;
        int l = (wy * 16 + (q >> 4)) * 128 + wxx * 16 + (q & 15);
        int col = n0 + wn * 48 + ni * 16 + h;
        size_t di = ((size_t)(bb * 16384 + l)) * 192 + col;
        float s1 = st[bb * 2 + 1];
        float val = bf2f(xb[di]) + s1 * ls1[col] * (acc[mi][ni][r] + wb[col]);
        x1b[di] = f2bf(val);
        ps += val;
        ps2 += val * val;
      }
  red[tid] = ps; red[256 + tid] = ps2;
  __syncthreads();
  for (int s = 128; s > 0; s >>= 1) {
    if (tid < s) { red[tid] += red[tid + s]; red[256 + tid] += red[256 + tid + s]; }
    __syncthreads();
  }
  if (tid == 0) {
    int pi = blockIdx.x * 2 + by;
    part2[pi * 2] = red[0];
    part2[pi * 2 + 1] = red[256];
  }
}

// ---------------- fcgv GEMM: barrier-free fragment loop + SiLU -> planar hp ----------------
__global__ __launch_bounds__(256) void gemm_fcgv(const short* __restrict__ x1n,
                                                 const short* __restrict__ wg,
                                                 const float* __restrict__ wb,
                                                 short* __restrict__ hp) {
  __shared__ short T[64 * 136];
  const int mt = blockIdx.x, by = blockIdx.y, n0 = by * 64;
  const int m0 = mt * 128;
  const int b = m0 >> 14, l0 = m0 & 16383;
  const int tid = threadIdx.x, wid = tid >> 6, lane = tid & 63;
  const int g = lane >> 4, h = lane & 15;
  const int wm = wid >> 1, wn = wid & 1;
  fx4 accg[4][2], accv[4][2];
#pragma unroll
  for (int i = 0; i < 4; i++)
#pragma unroll
    for (int j = 0; j < 2; j++) { accg[i][j] = fzero(); accv[i][j] = fzero(); }

#pragma unroll
  for (int kt = 0; kt < 6; kt++) {
    bh8 af[4], bg[2], bv[2];
#pragma unroll
    for (int mi = 0; mi < 4; mi++)
      af[mi] = *(const bh8*)(x1n + (size_t)((((mt * 2 + wm) * 4 + mi) * 6 + kt)) * 512 + lane * 8);
#pragma unroll
    for (int ni = 0; ni < 2; ni++) {
      size_t base = (size_t)((((by * 6 + kt) * 2 + wn) * 2 + ni) * 2) * 512;
      bg[ni] = *(const bh8*)(wg + base + lane * 8);
      bv[ni] = *(const bh8*)(wg + base + 512 + lane * 8);
    }
#pragma unroll
    for (int ni = 0; ni < 2; ni++)
#pragma unroll
      for (int mi = 0; mi < 4; mi++) {
        accg[mi][ni] = mfma16(af[mi], bg[ni], accg[mi][ni]);
        accv[mi][ni] = mfma16(af[mi], bv[ni], accv[mi][ni]);
      }
  }
  short hs[4][2][4];
#pragma unroll
  for (int mi = 0; mi < 4; mi++)
#pragma unroll
    for (int ni = 0; ni < 2; ni++)
#pragma unroll
      for (int r = 0; r < 4; r++) {
        int colg = n0 + wn * 32 + ni * 16 + h;
        float gv = accg[mi][ni][r] + wb[colg];
        float vv = accv[mi][ni][r] + wb[512 + colg];
        hs[mi][ni][r] = f2bf(gv / (1.f + __expf(-gv)) * vv);
      }
#pragma unroll
  for (int mi = 0; mi < 4; mi++)
#pragma unroll
    for (int ni = 0; ni < 2; ni++)
#pragma unroll
      for (int r = 0; r < 4; r++) {
        int cc = wn * 32 + ni * 16 + h;
        int rl = wm * 64 + mi * 16 + g * 4 + r;
        T[cc * 136 + rl] = hs[mi][ni][r];
      }
  __syncthreads();
#pragma unroll
  for (int i = 0; i < 4; i++) {
    int ch = tid + i * 256;
    int cc = ch >> 4, lg = ch & 15;
    bh8 v = *(bh8*)&T[cc * 136 + lg * 8];
    *(bh8*)(hp + (((size_t)(b * 512 + n0 + cc)) << 14) + l0 + lg * 8) = v;
  }
}

// ---------------- fused depthwise convs: 64-row stripes, out-of-place ----------------
__global__ __launch_bounds__(256) void dw_fused(const short* __restrict__ in,
                                                const float* __restrict__ w1,
                                                const float* __restrict__ b1,
                                                const float* __restrict__ w2,
                                                const float* __restrict__ b2,
                                                const float* __restrict__ dsc,
                                                short* __restrict__ outp) {
  __shared__ short P[70 * 136];
  __shared__ short D[68 * 136];
  const int p = blockIdx.x >> 1, s = blockIdx.x & 1, c = p & 511;
  const int tid = threadIdx.x;
  const int r0 = s * 64;
  const int plo = s ? 61 : 0;
  const int pbase = r0 - 3;
  const int dlo = s ? 62 : 0;
  const int dbase = r0 - 2;
  const short* ip = in + ((size_t)p << 14);

  for (int i = tid; i < 67 * 16; i += 256) {
    int rr = plo + (i >> 4), sl = i & 15;
    bh8 v = *(const bh8*)(ip + rr * 128 + sl * 8);
    *(bh8*)&P[(rr - pbase) * 136 + sl * 8] = v;
  }
  float k1[9], k2[9];
#pragma unroll
  for (int j = 0; j < 9; j++) { k1[j] = w1[c * 9 + j]; k2[j] = w2[c * 9 + j]; }
  const float bias1 = b1[c], bias2 = b2[c], ds = dsc[0];
  __syncthreads();

  for (int i = tid; i < 66 * 16; i += 256) {
    int gy = dlo + (i >> 4);
    int x0 = (i & 15) * 8;
    float acc[8];
#pragma unroll
    for (int q = 0; q < 8; q++) acc[q] = bias1;
#pragma unroll
    for (int ky = 0; ky < 3; ky++) {
      int yy = gy + ky - 1;
      if ((unsigned)yy < 128u) {
        const short* row = &P[(yy - pbase) * 136];
        float f[10];
        bh8 v = *(const bh8*)&row[x0];
#pragma unroll
        for (int j = 0; j < 8; j++) f[j + 1] = bf2f(v[j]);
        f[0] = (x0 == 0) ? 0.f : bf2f(row[x0 - 1]);
        f[9] = (x0 == 120) ? 0.f : bf2f(row[x0 + 8]);
        float w0 = k1[ky * 3], wA = k1[ky * 3 + 1], wB = k1[ky * 3 + 2];
#pragma unroll
        for (int q = 0; q < 8; q++) acc[q] += f[q] * w0 + f[q + 1] * wA + f[q + 2] * wB;
      }
    }
    bh8 pk;
#pragma unroll
    for (int q = 0; q < 8; q++) pk[q] = f2bf(acc[q]);
    *(bh8*)&D[(gy - dbase) * 136 + x0] = pk;
  }
  __syncthreads();

  for (int i = tid; i < 64 * 16; i += 256) {
    int gy = r0 + (i >> 4);
    int x0 = (i & 15) * 8;
    float acc[8], center[8];
#pragma unroll
    for (int q = 0; q < 8; q++) acc[q] = bias2;
#pragma unroll
    for (int ky = 0; ky < 3; ky++) {
      int yy = gy + (ky - 1) * 2;
      if ((unsigned)yy < 128u) {
        const short* row = &D[(yy - dbase) * 136];
        float f[12];
        bh8 v = *(const bh8*)&row[x0];
#pragma unroll
        for (int j = 0; j < 8; j++) f[j + 2] = bf2f(v[j]);
        if (x0 == 0) { f[0] = 0.f; f[1] = 0.f; }
        else {
          unsigned lp = *(const unsigned*)&row[x0 - 2];
          f[0] = __builtin_bit_cast(float, lp << 16);
          f[1] = __builtin_bit_cast(float, lp & 0xffff0000u);
        }
        if (x0 == 120) { f[10] = 0.f; f[11] = 0.f; }
        else {
          unsigned rp = *(const unsigned*)&row[x0 + 8];
          f[10] = __builtin_bit_cast(float, rp << 16);
          f[11] = __builtin_bit_cast(float, rp & 0xffff0000u);
        }
        float w0 = k2[ky * 3], wA = k2[ky * 3 + 1], wB = k2[ky * 3 + 2];
#pragma unroll
        for (int q = 0; q < 8; q++) acc[q] += f[q] * w0 + f[q + 2] * wA + f[q + 4] * wB;
        if (ky == 1) {
#pragma unroll
          for (int q = 0; q < 8; q++) center[q] = f[q + 2];
        }
      }
    }
    bh8 pk;
#pragma unroll
    for (int q = 0; q < 8; q++) pk[q] = f2bf(center[q] + ds * acc[q]);
    *(bh8*)(outp + ((size_t)p << 14) + gy * 128 + x0) = pk;
  }
}

// ---------------- fco GEMM: A via LDS transpose, B fragments, bf16 residual ----------------
__global__ __launch_bounds__(256) void gemm_fco(const short* __restrict__ h2,
                                                const short* __restrict__ wo,
                                                const float* __restrict__ wb,
                                                const short* __restrict__ x1b,
                                                const float* __restrict__ ls2,
                                                const float* __restrict__ st,
                                                float* __restrict__ out) {
  __shared__ short As[128 * 40];
  const int m0 = blockIdx.x * 128, by = blockIdx.y, n0 = by * 96;
  const int b = m0 >> 14, l0 = m0 & 16383;
  const int tid = threadIdx.x, wid = tid >> 6, lane = tid & 63;
  const int g = lane >> 4, h = lane & 15;
  const int wm = wid >> 1, wn = wid & 1;
  const int cp = tid & 15, lg = tid >> 4;
  fx4 acc[4][3];
#pragma unroll
  for (int i = 0; i < 4; i++)
#pragma unroll
    for (int j = 0; j < 3; j++) acc[i][j] = fzero();

  for (int kt = 0; kt < 16; kt++) {
    const int k0 = kt * 32;
    {
      const short* basep = h2 + (((size_t)(b * 512 + k0 + 2 * cp)) << 14) + l0 + lg * 8;
      bh8 v0 = *(const bh8*)basep;
      bh8 v1 = *(const bh8*)(basep + 16384);
#pragma unroll
      for (int j = 0; j < 8; j++) {
        unsigned pkv = (unsigned)(unsigned short)v0[j] | (((unsigned)(unsigned short)v1[j]) << 16);
        *(unsigned*)&As[(lg * 8 + j) * 40 + 2 * cp] = pkv;
      }
    }
    __syncthreads();
    bh8 af[4], bf[3];
#pragma unroll
    for (int mi = 0; mi < 4; mi++)
      af[mi] = *(bh8*)&As[(wm * 64 + mi * 16 + h) * 40 + g * 8];
#pragma unroll
    for (int ni = 0; ni < 3; ni++)
      bf[ni] = *(const bh8*)(wo + (size_t)(((by * 16 + kt) * 2 + wn) * 3 + ni) * 512 + lane * 8);
#pragma unroll
    for (int ni = 0; ni < 3; ni++)
#pragma unroll
      for (int mi = 0; mi < 4; mi++) acc[mi][ni] = mfma16(af[mi], bf[ni], acc[mi][ni]);
    __syncthreads();
  }
  float s2 = st[b * 2 + 1];
#pragma unroll
  for (int mi = 0; mi < 4; mi++)
#pragma unroll
    for (int ni = 0; ni < 3; ni++)
#pragma unroll
      for (int r = 0; r < 4; r++) {
        int row = m0 + wm * 64 + mi * 16 + g * 4 + r;
        int col = n0 + wn * 48 + ni * 16 + h;
        size_t di = (size_t)row * 192 + col;
        out[di] = bf2f(x1b[di]) + s2 * ls2[col] * (acc[mi][ni][r] + wb[col]);
      }
}

extern "C" void kernel_launch(void* const* d_in, const int* in_sizes, int n_in,
                              void* d_out, int out_size, void* d_ws, size_t ws_size,
                              hipStream_t stream) {
  const float* x      = (const float*)d_in[0];
  const float* qkv_w  = (const float*)d_in[1];
  const float* qkv_b  = (const float*)d_in[2];
  const float* proj_w = (const float*)d_in[3];
  const float* proj_b = (const float*)d_in[4];
  const float* rpb    = (const float*)d_in[5];
  const float* n1_w   = (const float*)d_in[6];
  const float* n1_b   = (const float*)d_in[7];
  const float* ls1    = (const float*)d_in[8];
  const float* n2_w   = (const float*)d_in[9];
  const float* n2_b   = (const float*)d_in[10];
  const float* ls2    = (const float*)d_in[11];
  const float* fcgv_w = (const float*)d_in[12];
  const float* fcgv_b = (const float*)d_in[13];
  const float* dw_w   = (const float*)d_in[14];
  const float* dw_b   = (const float*)d_in[15];
  const float* dwd_w  = (const float*)d_in[16];
  const float* dwd_b  = (const float*)d_in[17];
  const float* dil    = (const float*)d_in[18];
  const float* fco_w  = (const float*)d_in[19];
  const float* fco_b  = (const float*)d_in[20];
  float* out = (float*)d_out;
  char* ws = (char*)d_ws;

  // workspace layout (bytes); peak ~122.2 MB
  short* wbuf = (short*)(ws + 0);
  short* wq = wbuf;
  short* wp = wbuf + 110592;
  short* wg = wbuf + 147456;
  short* wo = wbuf + 344064;
  float* part  = (float*)(ws + 884736);
  float* st1   = (float*)(ws + 891904);
  float* st2   = (float*)(ws + 891968);
  float* part2 = (float*)(ws + 892032);
  short* xn  = (short*)(ws + 1048576);       // 12.58 MB (dead after qkv)
  short* btb = (short*)(ws + 13631488);      // 1.77 MB (dead after attn)
  short* qb  = (short*)(ws + 17301504);      // 12.58 MB (dead after attn)
  short* kb  = (short*)(ws + 29884416);      // 12.58 MB (dead after attn)
  short* vb  = (short*)(ws + 42467328);      // 12.58 MB (dead after attn)
  short* ao  = (short*)(ws + 55050240);      // 12.58 MB (dead after proj)
  short* x1b = (short*)(ws + 1048576);       // 12.58 MB bf16 (over xn, dead after qkv)
  short* x1n = (short*)(ws + 26214400);      // 12.58 MB fragment order (over qb-tail/kb-head)
  short* hp  = (short*)(ws + 42467328);      // 33.55 MB (over vb+ao)
  short* h2  = (short*)(ws + 76021760);      // 33.55 MB dw output
  short* xb  = (short*)(ws + 109576192);     // 12.58 MB bf16 copy of x

  iln_partial<<<512, 256, 0, stream>>>(x, part, xb);
  prep<<<432, 256, 0, stream>>>(qkv_w, proj_w, fcgv_w, fco_w, rpb, wbuf, btb);
  cvt_affb<<<3072, 256, 0, stream>>>(xb, part, n1_w, n1_b, xn, st1);
  gemm_qkv<<<dim3(256, 6), 256, 0, stream>>>(xn, wq, qkv_b, qb, kb, vb);
  attn_kernel<<<dim3(128, 6), 256, 0, stream>>>(qb, kb, vb, btb, ao);
  gemm_proj<<<dim3(256, 2), 256, 0, stream>>>(ao, wp, proj_b, xb, ls1, st1, x1b, part2);
  cvt_affb<<<3072, 256, 0, stream>>>(x1b, part2, n2_w, n2_b, x1n, st2);
  gemm_fcgv<<<dim3(256, 8), 256, 0, stream>>>(x1n, wg, fcgv_b, hp);
  dw_fused<<<2048, 256, 0, stream>>>(hp, dw_w, dw_b, dwd_w, dwd_b, dil, h2);
  gemm_fco<<<dim3(256, 2), 256, 0, stream>>>(h2, wo, fco_b, x1b, ls2, st2, out);
}